// Round 14
// baseline (188.243 us; speedup 1.0000x reference)
//
#include <hip/hip_runtime.h>
#include <hip/hip_bf16.h>
#include <math.h>

#define BN 1024
#define DIN 64
#define HD 128
#define EN 8192
#define SLOTS_STRIDE 64
#define MMR4 4
#define EGR 8
#define NC 128

typedef unsigned long long u64;

__global__ void k_fill(const int* dst, int* cnt, int* slots) {
    int e = blockIdx.x * blockDim.x + threadIdx.x;
    if (e < EN) {
        int d = dst[e];
        int p = atomicAdd(&cnt[d], 1);
        if (p < SLOTS_STRIDE) slots[d * SLOTS_STRIDE + p] = e;
    }
}

// FUSED: blocks 0..3 = per-node CSR sort + dinv; blocks 4..259 = mm1 (xw = mu @ W1)
struct FinMmSm {
    union {
        int buf[256][65];
        struct { float Wl[DIN * HD]; float xr[MMR4][DIN]; } m;
    } u;
};
__global__ __launch_bounds__(256) void k_finmm1(int* slots, const int* cnt, float* dinv,
                                                const float* mu, const float* W1, float* xw) {
    __shared__ FinMmSm sm;
    int tid = threadIdx.x;
    if (blockIdx.x < 4) {
        int t = blockIdx.x * 256 + tid;
        int n = cnt[t];
        if (n > SLOTS_STRIDE) n = SLOTS_STRIDE;
        for (int k = 0; k < n; k++) sm.u.buf[tid][k] = slots[t * SLOTS_STRIDE + k];
        for (int k = 1; k < n; k++) {
            int v = sm.u.buf[tid][k];
            int q = k - 1;
            while (q >= 0 && sm.u.buf[tid][q] > v) { sm.u.buf[tid][q + 1] = sm.u.buf[tid][q]; q--; }
            sm.u.buf[tid][q + 1] = v;
        }
        for (int k = 0; k < n; k++) slots[t * SLOTS_STRIDE + k] = sm.u.buf[tid][k];
        dinv[t] = 1.0f / sqrtf(fmaxf((float)(n + 1), 1e-12f));
    } else {
        int r0 = (blockIdx.x - 4) * MMR4;
        for (int idx = tid; idx < DIN * HD / 4; idx += 256)
            ((float4*)sm.u.m.Wl)[idx] = ((const float4*)W1)[idx];
        for (int idx = tid; idx < MMR4 * DIN / 4; idx += 256) {
            float4 v = ((const float4*)(mu + r0 * DIN))[idx];
            int row = (idx * 4) / DIN, col = (idx * 4) % DIN;
            sm.u.m.xr[row][col] = v.x; sm.u.m.xr[row][col + 1] = v.y;
            sm.u.m.xr[row][col + 2] = v.z; sm.u.m.xr[row][col + 3] = v.w;
        }
        __syncthreads();
        int col = tid & 127, half = tid >> 7;
        float a0 = 0.0f, a1 = 0.0f;
#pragma unroll 4
        for (int k = 0; k < DIN; k++) {
            float w = sm.u.m.Wl[k * HD + col];
            a0 = fmaf(sm.u.m.xr[half * 2 + 0][k], w, a0);
            a1 = fmaf(sm.u.m.xr[half * 2 + 1][k], w, a1);
        }
        xw[(r0 + half * 2 + 0) * HD + col] = a0;
        xw[(r0 + half * 2 + 1) * HD + col] = a1;
    }
}

// mm with LDS-staged W (K=128): 4 rows/block, 256 threads
__global__ __launch_bounds__(256) void k_mm128(const float* x, const float* W, float* out) {
    __shared__ float Wl[HD * HD];
    __shared__ float xr[MMR4][HD];
    int tid = threadIdx.x;
    int r0 = blockIdx.x * MMR4;
    for (int idx = tid; idx < HD * HD / 4; idx += 256)
        ((float4*)Wl)[idx] = ((const float4*)W)[idx];
    for (int idx = tid; idx < MMR4 * HD / 4; idx += 256) {
        float4 v = ((const float4*)(x + r0 * HD))[idx];
        int row = idx >> 5, col = (idx & 31) * 4;
        xr[row][col] = v.x; xr[row][col + 1] = v.y; xr[row][col + 2] = v.z; xr[row][col + 3] = v.w;
    }
    __syncthreads();
    int col = tid & 127, half = tid >> 7;
    float a0 = 0.0f, a1 = 0.0f;
#pragma unroll 4
    for (int k = 0; k < HD; k++) {
        float w = Wl[k * HD + col];
        a0 = fmaf(xr[half * 2 + 0][k], w, a0);
        a1 = fmaf(xr[half * 2 + 1][k], w, a1);
    }
    out[(r0 + half * 2 + 0) * HD + col] = a0;
    out[(r0 + half * 2 + 1) * HD + col] = a1;
}

// fused Aa/Cc with full Ws1 (128 KB) staged in LDS
__global__ __launch_bounds__(256) void k_mmAC(const float* h, const float* Ws1, const float* bs1,
                                              float* Aa, float* Cc) {
    __shared__ float Wl[2 * HD * HD];
    __shared__ float xr[MMR4][HD];
    int tid = threadIdx.x;
    int r0 = blockIdx.x * MMR4;
    for (int idx = tid; idx < 2 * HD * HD / 4; idx += 256)
        ((float4*)Wl)[idx] = ((const float4*)Ws1)[idx];
    for (int idx = tid; idx < MMR4 * HD / 4; idx += 256) {
        float4 v = ((const float4*)(h + r0 * HD))[idx];
        int row = idx >> 5, col = (idx & 31) * 4;
        xr[row][col] = v.x; xr[row][col + 1] = v.y; xr[row][col + 2] = v.z; xr[row][col + 3] = v.w;
    }
    __syncthreads();
    int col = tid & 127, half = tid >> 7;
    float bc = bs1[col];
    float A0 = 0.0f, A1 = 0.0f, C0 = bc, C1 = bc;
#pragma unroll 2
    for (int k = 0; k < HD; k++) {
        float wa = Wl[k * HD + col];
        float wc = Wl[(HD + k) * HD + col];
        A0 = fmaf(xr[half * 2 + 0][k], wa, A0);
        A1 = fmaf(xr[half * 2 + 1][k], wa, A1);
        C0 = fmaf(xr[half * 2 + 0][k], wc, C0);
        C1 = fmaf(xr[half * 2 + 1][k], wc, C1);
    }
    Aa[(r0 + half * 2 + 0) * HD + col] = A0;
    Aa[(r0 + half * 2 + 1) * HD + col] = A1;
    Cc[(r0 + half * 2 + 0) * HD + col] = C0;
    Cc[(r0 + half * 2 + 1) * HD + col] = C1;
}

// GCN gather: parallel edge-list prefetch + unrolled accumulate
__global__ __launch_bounds__(128) void k_gather(const float* xw, const float* bvec, const int* src,
                                                const int* slots, const int* cnt,
                                                const float* dinv, float* hout) {
    __shared__ int sn_s[SLOTS_STRIDE];
    __shared__ float w_s[SLOTS_STRIDE];
    int d = blockIdx.x, t = threadIdx.x;
    float dd = dinv[d];
    int n = cnt[d];
    if (n > SLOTS_STRIDE) n = SLOTS_STRIDE;
    if (t < n) {
        int e = slots[d * SLOTS_STRIDE + t];
        int sn = src[e];
        sn_s[t] = sn;
        w_s[t] = dinv[sn] * dd;
    }
    __syncthreads();
    float acc = 0.0f;
#pragma unroll 4
    for (int s = 0; s < n; s++)
        acc = fmaf(xw[sn_s[s] * HD + t], w_s[s], acc);
    acc = fmaf(xw[d * HD + t], dd * dd, acc);
    acc += bvec[t];
    hout[d * HD + t] = fmaxf(acc, 0.0f);
}

__device__ __forceinline__ u64 edge_key(float w, int i, int j) {
    unsigned u = __float_as_uint(w);
    u = (u & 0x80000000u) ? ~u : (u | 0x80000000u);
    int a = i < j ? i : j, b = i < j ? j : i;
    unsigned packed = (unsigned)(a * BN + b);
    return ((u64)u << 20) | (u64)(0xFFFFFu - packed);
}

// ---- shared device helpers for elected-block merge ----
__device__ void merge_body(int tid, int* pa, int* pb, int* comp, u64* best,
                           u64* mst, int* mstcnt) {
    for (int c = tid; c < BN; c += 256) {
        int myComp = comp[c];
        bool root = (myComp == c);
        u64 e = best[c];
        int t = c;
        if (root && e) {
            unsigned packed = 0xFFFFFu - (unsigned)(e & 0xFFFFFu);
            int a = packed >> 10, b = packed & 1023;
            int ca = comp[a], cb = comp[b];
            t = (ca == c) ? cb : ca;
        }
        pa[c] = (root && e) ? t : c;
    }
    __syncthreads();
    for (int c = tid; c < BN; c += 256) {
        bool root = (comp[c] == c);
        u64 e = best[c];
        int p0 = pa[c];
        if (root && e) {
            int t = pa[c];
            bool mutual = (pa[t] == c);
            if (mutual && c < t) p0 = c;
            if (!(mutual && c > t)) {
                int idx = atomicAdd(mstcnt, 1);
                mst[idx] = e;
            }
        }
        pb[c] = p0;
    }
    __syncthreads();
    for (int c = tid; c < BN; c += 256) pa[c] = pb[c];
    __syncthreads();
    for (int it = 0; it < 10; it++) {
        for (int c = tid; c < BN; c += 256) pb[c] = pa[pa[c]];
        __syncthreads();
        for (int c = tid; c < BN; c += 256) pa[c] = pb[c];
        __syncthreads();
    }
    for (int c = tid; c < BN; c += 256) {
        comp[c] = pa[comp[c]];
        best[c] = 0ull;
    }
    __syncthreads();
}

// ballot-based dense renumber of roots (2 barriers); masksS = 16-u64 LDS
__device__ void renumber_body(int tid, u64* masksS, const int* comp, int* compD, int* ncompG) {
    int lane = tid & 63, wv = tid >> 6;
    for (int chunk = wv; chunk < 16; chunk += 4) {
        int c2 = chunk * 64 + lane;
        u64 m = __ballot(comp[c2] == c2);
        if (lane == 0) masksS[chunk] = m;
    }
    __syncthreads();
    for (int c2 = tid; c2 < BN; c2 += 256) {
        int r = comp[c2];
        int chunk = r >> 6;
        int rk = 0;
        for (int k = 0; k < chunk; k++) rk += __popcll(masksS[k]);
        rk += __popcll(masksS[chunk] & ((1ull << (r & 63)) - 1ull));
        compD[c2] = rk;
    }
    if (tid == 0) {
        int nc2 = 0;
        for (int k = 0; k < 16; k++) nc2 += __popcll(masksS[k]);
        *ncompG = nc2;
    }
}

// scores + fused round-1 best + ELECTED-BLOCK merge1
__global__ __launch_bounds__(256) void k_scores(const float* Aa, const float* Cc,
                                                const float* Ws2, const float* bs2v,
                                                float* S, u64* best, int* done,
                                                int* comp, u64* mst, int* mstcnt) {
    int bid = blockIdx.x;
    int bi = 0, rem = bid;
    while (rem >= 16 - bi) { rem -= 16 - bi; bi++; }
    int bj = bi + rem;
    __shared__ float As[64][68];
    __shared__ float Cs[64][68];
    __shared__ float w2[HD];
    __shared__ u64 rmax[64], cmax[64];
    __shared__ int pa[BN], pb[BN];
    __shared__ int isLast;
    int tid = threadIdx.x;
    int R = bi * 64, Cb = bj * 64;
    if (tid < HD) w2[tid] = Ws2[tid];
    if (tid < 64) { rmax[tid] = 0ull; cmax[tid] = 0ull; }
    int tx = tid & 15, ty = tid >> 4;
    float acc[4][4] = {};
    for (int half = 0; half < 2; half++) {
        int k0 = half * 64;
        __syncthreads();
        for (int f = tid; f < 1024; f += 256) {
            int row = f >> 4, kk4 = (f & 15) * 4;
            float4 a = *(const float4*)&Aa[(R + row) * HD + k0 + kk4];
            float4 c = *(const float4*)&Cc[(Cb + row) * HD + k0 + kk4];
            As[kk4 + 0][row] = a.x; As[kk4 + 1][row] = a.y;
            As[kk4 + 2][row] = a.z; As[kk4 + 3][row] = a.w;
            Cs[kk4 + 0][row] = c.x; Cs[kk4 + 1][row] = c.y;
            Cs[kk4 + 2][row] = c.z; Cs[kk4 + 3][row] = c.w;
        }
        __syncthreads();
        for (int kk = 0; kk < 64; kk++) {
            float4 av = *(const float4*)&As[kk][ty * 4];
            float4 cv = *(const float4*)&Cs[kk][tx * 4];
            float wk = w2[k0 + kk];
            float ar[4] = {av.x, av.y, av.z, av.w};
            float cr[4] = {cv.x, cv.y, cv.z, cv.w};
#pragma unroll
            for (int r = 0; r < 4; r++)
#pragma unroll
                for (int q = 0; q < 4; q++) {
                    float tv = fmaxf(ar[r] + cr[q], 0.0f);
                    acc[r][q] = fmaf(tv, wk, acc[r][q]);
                }
        }
    }
    float b2 = bs2v[0];
    u64 rloc[4] = {0ull, 0ull, 0ull, 0ull};
    u64 cloc[4] = {0ull, 0ull, 0ull, 0ull};
#pragma unroll
    for (int r = 0; r < 4; r++)
#pragma unroll
        for (int q = 0; q < 4; q++) {
            int gr = R + ty * 4 + r, gc = Cb + tx * 4 + q;
            float v = acc[r][q] + b2;
            if (gr < gc) {
                S[gr * BN + gc] = v;
                S[gc * BN + gr] = v;
                u64 key = edge_key(v, gr, gc);
                if (key > rloc[r]) rloc[r] = key;
                if (key > cloc[q]) cloc[q] = key;
            } else if (gr == gc) S[gr * BN + gc] = 0.0f;
        }
#pragma unroll
    for (int r = 0; r < 4; r++) {
        if (rloc[r]) atomicMax(&rmax[ty * 4 + r], rloc[r]);
        if (cloc[r]) atomicMax(&cmax[tx * 4 + r], cloc[r]);
    }
    __syncthreads();
    if (tid < 64) {
        if (rmax[tid]) atomicMax(&best[R + tid], rmax[tid]);
    } else if (tid < 128) {
        if (cmax[tid - 64]) atomicMax(&best[Cb + tid - 64], cmax[tid - 64]);
    }
    // ---- election (no spin: losers return; bounded work only) ----
    __threadfence();
    __syncthreads();
    if (tid == 0) { int v = atomicAdd(done, 1); isLast = (v == (int)gridDim.x - 1); }
    __syncthreads();
    if (!isLast) return;
    __threadfence();
    // ---- merge round 1 (comp = identity; every node has best) ----
    for (int c = tid; c < BN; c += 256) {
        u64 e = best[c];
        unsigned packed = 0xFFFFFu - (unsigned)(e & 0xFFFFFu);
        int a = packed >> 10, b = packed & 1023;
        pa[c] = (a == c) ? b : a;
    }
    __syncthreads();
    for (int c = tid; c < BN; c += 256) {
        int t = pa[c];
        bool mutual = (pa[t] == c);
        int p0 = (mutual && c < t) ? c : t;
        if (!(mutual && c > t)) {
            int idx = atomicAdd(mstcnt, 1);
            mst[idx] = best[c];
        }
        pb[c] = p0;
    }
    __syncthreads();
    for (int c = tid; c < BN; c += 256) pa[c] = pb[c];
    __syncthreads();
    for (int it = 0; it < 10; it++) {
        for (int c = tid; c < BN; c += 256) pb[c] = pa[pa[c]];
        __syncthreads();
        for (int c = tid; c < BN; c += 256) pa[c] = pb[c];
        __syncthreads();
    }
    for (int c = tid; c < BN; c += 256) {
        comp[c] = pa[c];
        best[c] = 0ull;
    }
}

// best scan + ELECTED-BLOCK merge (emitDense via ballot renumber)
__global__ __launch_bounds__(256) void k_bestm(const float* S, int* comp, u64* best,
                                               u64* mst, int* mstcnt, int* compD,
                                               int* ncompG, int* done, int ncGuard) {
    __shared__ int pa[BN], pb[BN];
    __shared__ u64 masksS[16];
    __shared__ int isLast;
    int tid = threadIdx.x;
    if (*mstcnt >= BN - 1) return;
    if (ncGuard && *ncompG <= NC) return;
    {
        int lane = tid & 63;
        int i = blockIdx.x * 4 + (tid >> 6);
        int ci = comp[i];
        const float* Srow = S + (size_t)i * BN;
        u64 loc = 0ull;
#pragma unroll 4
        for (int j = lane; j < BN; j += 64)
            if (comp[j] != ci) {
                u64 key = edge_key(Srow[j], i, j);
                if (key > loc) loc = key;
            }
#pragma unroll
        for (int off = 32; off > 0; off >>= 1) {
            u64 o = __shfl_xor(loc, off);
            if (o > loc) loc = o;
        }
        if (lane == 0 && loc) atomicMax(&best[ci], loc);
    }
    __threadfence();
    __syncthreads();
    if (tid == 0) { int v = atomicAdd(done, 1); isLast = (v == (int)gridDim.x - 1); }
    __syncthreads();
    if (!isLast) return;
    __threadfence();
    merge_body(tid, pa, pb, comp, best, mst, mstcnt);
    renumber_body(tid, masksS, comp, compD, ncompG);
}

// fused G+Sp: per-row LDS table -> global atomicMax into sp[c1][c2] (pre-zeroed)
__global__ __launch_bounds__(256) void k_Gsp(const float* S, const int* compD,
                                             const int* mstcnt, u64* spG) {
    if (*mstcnt >= BN - 1) return;
    __shared__ u64 t[NC];
    int tid = threadIdx.x;
    int i = blockIdx.x;
    int ci = compD[i];
    if (tid < NC) t[tid] = 0ull;
    __syncthreads();
    const float* Srow = S + (size_t)i * BN;
#pragma unroll 2
    for (int j = tid; j < BN; j += 256) {
        int cj = compD[j];
        if (j != i && cj != ci) atomicMax(&t[cj], edge_key(Srow[j], i, j));
    }
    __syncthreads();
    if (tid < NC && t[tid]) atomicMax(&spG[(size_t)ci * NC + tid], t[tid]);
}

struct FinSm {
    union {
        u64 sp[NC][NC];
        u64 sk[BN];
    } u;
    int cnd[BN];
    int ccomp[NC], cpa[NC], cpb[NC];
    u64 cbest[NC];
    int lcnt;
};

// remaining Boruvka rounds on the contracted (<=128 node) graph + finale
__global__ __launch_bounds__(1024) void k_mstfin(const u64* spG, const int* compD,
                                                 const int* ncompG, const int* mstcntG,
                                                 u64* mstG, float* out, int* pairs) {
    __shared__ FinSm sm;
    int c = threadIdx.x;
    int total = *mstcntG;
    if (total < BN - 1) {
        int nc = *ncompG;
        for (int idx = c; idx < NC * NC; idx += 1024) ((u64*)sm.u.sp)[idx] = spG[idx];
        sm.cnd[c] = compD[c];
        if (c < NC) { sm.ccomp[c] = c; sm.cbest[c] = 0ull; }
        if (c == 0) sm.lcnt = 0;
        __syncthreads();
        for (int rr = 0; rr < 8 && total < BN - 1; rr++) {
            if (c < nc) {
                int g = sm.ccomp[c];
                u64 m = 0ull;
                for (int c2 = 0; c2 < nc; c2++)
                    if (sm.ccomp[c2] != g) {
                        u64 v = sm.u.sp[c][c2];
                        if (v > m) m = v;
                    }
                if (m) atomicMax(&sm.cbest[g], m);
            }
            __syncthreads();
            if (c < nc) {
                bool root = (sm.ccomp[c] == c);
                u64 e = sm.cbest[c];
                int t2 = c;
                if (root && e) {
                    unsigned packed = 0xFFFFFu - (unsigned)(e & 0xFFFFFu);
                    int a = packed >> 10, b = packed & 1023;
                    int ga = sm.ccomp[sm.cnd[a]], gb = sm.ccomp[sm.cnd[b]];
                    t2 = (ga == c) ? gb : ga;
                }
                sm.cpa[c] = (root && e) ? t2 : c;
            }
            __syncthreads();
            if (c < nc) {
                bool root = (sm.ccomp[c] == c);
                u64 e = sm.cbest[c];
                int t2 = sm.cpa[c];
                bool mutual = root && e && (sm.cpa[t2] == c);
                int p0 = sm.cpa[c];
                if (mutual && c < t2) p0 = c;
                sm.cpb[c] = p0;
                if (root && e && !(mutual && c > t2)) {
                    int idx = total + atomicAdd(&sm.lcnt, 1);
                    mstG[idx] = e;
                }
            }
            __syncthreads();
            if (c < nc) sm.cpa[c] = sm.cpb[c];
            __syncthreads();
            for (int it = 0; it < 7; it++) {
                if (c < nc) sm.cpb[c] = sm.cpa[sm.cpa[c]];
                __syncthreads();
                if (c < nc) sm.cpa[c] = sm.cpb[c];
                __syncthreads();
            }
            if (c < nc) {
                sm.ccomp[c] = sm.cpa[sm.ccomp[c]];
                sm.cbest[c] = 0ull;
            }
            __syncthreads();
            int added = sm.lcnt;
            __syncthreads();
            total += added;
            if (c == 0) sm.lcnt = 0;
            __syncthreads();
        }
    }
    __syncthreads();
    sm.u.sk[c] = (c < BN - 1) ? mstG[c] : 0ull;
    __syncthreads();
    if (c < BN - 1) {
        u64 mykey = sm.u.sk[c];
        int rk = 0;
        for (int f = 0; f < BN - 1; f++) rk += (sm.u.sk[f] > mykey) ? 1 : 0;
        unsigned packed = 0xFFFFFu - (unsigned)(mykey & 0xFFFFFu);
        int i = packed >> 10, j2 = packed & 1023;
        out[2 * rk] = (float)i;
        out[2 * rk + 1] = (float)j2;
        out[2046 + 2 * rk] = (float)j2;
        out[2046 + 2 * rk + 1] = (float)i;
        pairs[2 * rk] = i;
        pairs[2 * rk + 1] = j2;
    }
}

// gamma: 8 edges/block, Wg1 (128 KB) LDS-staged; Wg2 reuses the same buffer
struct GammaSm {
    float W[2 * HD * HD];
    float hp[EGR][2 * HD];
    float z1[EGR][HD];
};
__global__ __launch_bounds__(256) void k_gamma8(const float* h, const int* pairs,
                                                const float* Wg1, const float* bg1,
                                                const float* Wg2, const float* bg2, float* out) {
    __shared__ GammaSm sm;
    int tid = threadIdx.x;
    int e0 = blockIdx.x * EGR;
    for (int idx = tid; idx < 2 * HD * HD / 4; idx += 256)
        ((float4*)sm.W)[idx] = ((const float4*)Wg1)[idx];
    for (int idx = tid; idx < EGR * 2 * HD; idx += 256) {
        int eo = idx >> 8;
        int k = idx & 255;
        int e = e0 + eo;
        if (e < BN - 1) {
            int node = (k < HD) ? pairs[2 * e] : pairs[2 * e + 1];
            sm.hp[eo][k] = h[node * HD + (k & 127)];
        } else sm.hp[eo][k] = 0.0f;
    }
    __syncthreads();
    {
        int c = tid & 127, eg = tid >> 7;
        float b = bg1[c];
        float a0 = b, a1 = b, a2 = b, a3 = b;
#pragma unroll 8
        for (int k = 0; k < 2 * HD; k++) {
            float w = sm.W[k * HD + c];
            a0 = fmaf(sm.hp[eg * 4 + 0][k], w, a0);
            a1 = fmaf(sm.hp[eg * 4 + 1][k], w, a1);
            a2 = fmaf(sm.hp[eg * 4 + 2][k], w, a2);
            a3 = fmaf(sm.hp[eg * 4 + 3][k], w, a3);
        }
        sm.z1[eg * 4 + 0][c] = fmaxf(a0, 0.0f);
        sm.z1[eg * 4 + 1][c] = fmaxf(a1, 0.0f);
        sm.z1[eg * 4 + 2][c] = fmaxf(a2, 0.0f);
        sm.z1[eg * 4 + 3][c] = fmaxf(a3, 0.0f);
    }
    __syncthreads();
    for (int idx = tid; idx < HD * DIN / 4; idx += 256)
        ((float4*)sm.W)[idx] = ((const float4*)Wg2)[idx];
    __syncthreads();
    {
        int co = tid & 63, eh = tid >> 6;
        float b = bg2[co];
        float g0 = b, g1 = b;
#pragma unroll 8
        for (int k = 0; k < HD; k++) {
            float w = sm.W[k * DIN + co];
            g0 = fmaf(sm.z1[eh * 2 + 0][k], w, g0);
            g1 = fmaf(sm.z1[eh * 2 + 1][k], w, g1);
        }
        int ea = e0 + eh * 2, eb = ea + 1;
        if (ea < BN - 1) out[4092 + ea * DIN + co] = tanhf(g0);
        if (eb < BN - 1) out[4092 + eb * DIN + co] = tanhf(g1);
    }
}

extern "C" void kernel_launch(void* const* d_in, const int* in_sizes, int n_in,
                              void* d_out, int out_size, void* d_ws, size_t ws_size,
                              hipStream_t stream) {
    const float* mu  = (const float*)d_in[0];
    const int*   ei  = (const int*)d_in[1];
    const float* W1  = (const float*)d_in[2];
    const float* b1  = (const float*)d_in[3];
    const float* W2  = (const float*)d_in[4];
    const float* b2  = (const float*)d_in[5];
    const float* Ws1 = (const float*)d_in[6];
    const float* bs1 = (const float*)d_in[7];
    const float* Ws2 = (const float*)d_in[8];
    const float* bs2 = (const float*)d_in[9];
    const float* Wg1 = (const float*)d_in[10];
    const float* bg1 = (const float*)d_in[11];
    const float* Wg2 = (const float*)d_in[12];
    const float* bg2 = (const float*)d_in[13];
    float* out = (float*)d_out;

    const int* src = ei;
    const int* dst = ei + EN;

    char* ws = (char*)d_ws;
    int*   slots = (int*)(ws);                      // 256 KiB (aliases S, dead pre-scores)
    float* S     = (float*)(ws);                    // 4 MiB, born at k_scores
    float* xw    = (float*)(ws + 4194304);
    float* h1    = (float*)(ws + 4718592);
    float* h2    = (float*)(ws + 5242880);
    float* Aa    = (float*)(ws + 5767168);
    float* Cc    = (float*)(ws + 6291456);
    // contiguous memset region Z: [cnt | best | mstcnt | done | spG] = 151552 B
    int*   cnt    = (int*)(ws + 6815744);           // 4 KiB
    u64*   best   = (u64*)(ws + 6819840);           // 8 KiB
    int*   mstcnt = (int*)(ws + 6828032);           // 4 KiB (padded)
    int*   done   = (int*)(ws + 6832128);           // 4 KiB (3 slots used)
    u64*   spG    = (u64*)(ws + 6836224);           // 128 KiB
    // end memset region (ends 6967296)
    int*   comp  = (int*)(ws + 6967296);
    u64*   mstG  = (u64*)(ws + 6971392);
    int*   pairs = (int*)(ws + 6979584);
    int*   compD = (int*)(ws + 6987776);
    int*   ncomp = (int*)(ws + 6991872);
    float* dinv  = (float*)(ws + 6995968);

    hipMemsetAsync(ws + 6815744, 0, 151552, stream);

    k_fill<<<EN / 256, 256, 0, stream>>>(dst, cnt, slots);
    k_finmm1<<<260, 256, 0, stream>>>(slots, cnt, dinv, mu, W1, xw);
    k_gather<<<BN, HD, 0, stream>>>(xw, b1, src, slots, cnt, dinv, h1);
    k_mm128<<<BN / MMR4, 256, 0, stream>>>(h1, W2, xw);
    k_gather<<<BN, HD, 0, stream>>>(xw, b2, src, slots, cnt, dinv, h2);

    k_mmAC<<<BN / MMR4, 256, 0, stream>>>(h2, Ws1, bs1, Aa, Cc);

    // scores + best1 + elected merge1
    k_scores<<<136, 256, 0, stream>>>(Aa, Cc, Ws2, bs2, S, best, done + 0,
                                      comp, mstG, mstcnt);
    // round 2: best + elected merge (+dense renumber)
    k_bestm<<<BN / 4, 256, 0, stream>>>(S, comp, best, mstG, mstcnt, compD, ncomp,
                                        done + 256, 0);
    // round 3 (guarded: runs only if ncomp > 128)
    k_bestm<<<BN / 4, 256, 0, stream>>>(S, comp, best, mstG, mstcnt, compD, ncomp,
                                        done + 512, 1);

    k_Gsp<<<BN, 256, 0, stream>>>(S, compD, mstcnt, spG);
    k_mstfin<<<1, 1024, 0, stream>>>(spG, compD, ncomp, mstcnt, mstG, out, pairs);

    k_gamma8<<<(BN - 1 + EGR - 1) / EGR, 256, 0, stream>>>(h2, pairs, Wg1, bg1, Wg2, bg2, out);
}

// Round 15
// 152.976 us; speedup vs baseline: 1.2305x; 1.2305x over previous
//
#include <hip/hip_runtime.h>
#include <hip/hip_bf16.h>
#include <math.h>

#define BN 1024
#define DIN 64
#define HD 128
#define EN 8192
#define SLOTS_STRIDE 64
#define MMR4 4
#define EGR 8
#define NC 128

typedef unsigned long long u64;

__global__ void k_fill(const int* dst, int* cnt, int* slots) {
    int e = blockIdx.x * blockDim.x + threadIdx.x;
    if (e < EN) {
        int d = dst[e];
        int p = atomicAdd(&cnt[d], 1);
        if (p < SLOTS_STRIDE) slots[d * SLOTS_STRIDE + p] = e;
    }
}

// FUSED: blocks 0..3 = per-node CSR sort + dinv; blocks 4..259 = mm1 (xw = mu @ W1)
struct FinMmSm {
    union {
        int buf[256][65];
        struct { float Wl[DIN * HD]; float xr[MMR4][DIN]; } m;
    } u;
};
__global__ __launch_bounds__(256) void k_finmm1(int* slots, const int* cnt, float* dinv,
                                                const float* mu, const float* W1, float* xw) {
    __shared__ FinMmSm sm;
    int tid = threadIdx.x;
    if (blockIdx.x < 4) {
        int t = blockIdx.x * 256 + tid;
        int n = cnt[t];
        if (n > SLOTS_STRIDE) n = SLOTS_STRIDE;
        for (int k = 0; k < n; k++) sm.u.buf[tid][k] = slots[t * SLOTS_STRIDE + k];
        for (int k = 1; k < n; k++) {
            int v = sm.u.buf[tid][k];
            int q = k - 1;
            while (q >= 0 && sm.u.buf[tid][q] > v) { sm.u.buf[tid][q + 1] = sm.u.buf[tid][q]; q--; }
            sm.u.buf[tid][q + 1] = v;
        }
        for (int k = 0; k < n; k++) slots[t * SLOTS_STRIDE + k] = sm.u.buf[tid][k];
        dinv[t] = 1.0f / sqrtf(fmaxf((float)(n + 1), 1e-12f));
    } else {
        int r0 = (blockIdx.x - 4) * MMR4;
        for (int idx = tid; idx < DIN * HD / 4; idx += 256)
            ((float4*)sm.u.m.Wl)[idx] = ((const float4*)W1)[idx];
        for (int idx = tid; idx < MMR4 * DIN / 4; idx += 256) {
            float4 v = ((const float4*)(mu + r0 * DIN))[idx];
            int row = (idx * 4) / DIN, col = (idx * 4) % DIN;
            sm.u.m.xr[row][col] = v.x; sm.u.m.xr[row][col + 1] = v.y;
            sm.u.m.xr[row][col + 2] = v.z; sm.u.m.xr[row][col + 3] = v.w;
        }
        __syncthreads();
        int col = tid & 127, half = tid >> 7;
        float a0 = 0.0f, a1 = 0.0f;
#pragma unroll 4
        for (int k = 0; k < DIN; k++) {
            float w = sm.u.m.Wl[k * HD + col];
            a0 = fmaf(sm.u.m.xr[half * 2 + 0][k], w, a0);
            a1 = fmaf(sm.u.m.xr[half * 2 + 1][k], w, a1);
        }
        xw[(r0 + half * 2 + 0) * HD + col] = a0;
        xw[(r0 + half * 2 + 1) * HD + col] = a1;
    }
}

// mm with LDS-staged W (K=128): 4 rows/block, 256 threads
__global__ __launch_bounds__(256) void k_mm128(const float* x, const float* W, float* out) {
    __shared__ float Wl[HD * HD];
    __shared__ float xr[MMR4][HD];
    int tid = threadIdx.x;
    int r0 = blockIdx.x * MMR4;
    for (int idx = tid; idx < HD * HD / 4; idx += 256)
        ((float4*)Wl)[idx] = ((const float4*)W)[idx];
    for (int idx = tid; idx < MMR4 * HD / 4; idx += 256) {
        float4 v = ((const float4*)(x + r0 * HD))[idx];
        int row = idx >> 5, col = (idx & 31) * 4;
        xr[row][col] = v.x; xr[row][col + 1] = v.y; xr[row][col + 2] = v.z; xr[row][col + 3] = v.w;
    }
    __syncthreads();
    int col = tid & 127, half = tid >> 7;
    float a0 = 0.0f, a1 = 0.0f;
#pragma unroll 4
    for (int k = 0; k < HD; k++) {
        float w = Wl[k * HD + col];
        a0 = fmaf(xr[half * 2 + 0][k], w, a0);
        a1 = fmaf(xr[half * 2 + 1][k], w, a1);
    }
    out[(r0 + half * 2 + 0) * HD + col] = a0;
    out[(r0 + half * 2 + 1) * HD + col] = a1;
}

// fused Aa/Cc with full Ws1 (128 KB) staged in LDS
__global__ __launch_bounds__(256) void k_mmAC(const float* h, const float* Ws1, const float* bs1,
                                              float* Aa, float* Cc) {
    __shared__ float Wl[2 * HD * HD];
    __shared__ float xr[MMR4][HD];
    int tid = threadIdx.x;
    int r0 = blockIdx.x * MMR4;
    for (int idx = tid; idx < 2 * HD * HD / 4; idx += 256)
        ((float4*)Wl)[idx] = ((const float4*)Ws1)[idx];
    for (int idx = tid; idx < MMR4 * HD / 4; idx += 256) {
        float4 v = ((const float4*)(h + r0 * HD))[idx];
        int row = idx >> 5, col = (idx & 31) * 4;
        xr[row][col] = v.x; xr[row][col + 1] = v.y; xr[row][col + 2] = v.z; xr[row][col + 3] = v.w;
    }
    __syncthreads();
    int col = tid & 127, half = tid >> 7;
    float bc = bs1[col];
    float A0 = 0.0f, A1 = 0.0f, C0 = bc, C1 = bc;
#pragma unroll 2
    for (int k = 0; k < HD; k++) {
        float wa = Wl[k * HD + col];
        float wc = Wl[(HD + k) * HD + col];
        A0 = fmaf(xr[half * 2 + 0][k], wa, A0);
        A1 = fmaf(xr[half * 2 + 1][k], wa, A1);
        C0 = fmaf(xr[half * 2 + 0][k], wc, C0);
        C1 = fmaf(xr[half * 2 + 1][k], wc, C1);
    }
    Aa[(r0 + half * 2 + 0) * HD + col] = A0;
    Aa[(r0 + half * 2 + 1) * HD + col] = A1;
    Cc[(r0 + half * 2 + 0) * HD + col] = C0;
    Cc[(r0 + half * 2 + 1) * HD + col] = C1;
}

// GCN gather: parallel edge-list prefetch + unrolled accumulate
__global__ __launch_bounds__(128) void k_gather(const float* xw, const float* bvec, const int* src,
                                                const int* slots, const int* cnt,
                                                const float* dinv, float* hout) {
    __shared__ int sn_s[SLOTS_STRIDE];
    __shared__ float w_s[SLOTS_STRIDE];
    int d = blockIdx.x, t = threadIdx.x;
    float dd = dinv[d];
    int n = cnt[d];
    if (n > SLOTS_STRIDE) n = SLOTS_STRIDE;
    if (t < n) {
        int e = slots[d * SLOTS_STRIDE + t];
        int sn = src[e];
        sn_s[t] = sn;
        w_s[t] = dinv[sn] * dd;
    }
    __syncthreads();
    float acc = 0.0f;
#pragma unroll 4
    for (int s = 0; s < n; s++)
        acc = fmaf(xw[sn_s[s] * HD + t], w_s[s], acc);
    acc = fmaf(xw[d * HD + t], dd * dd, acc);
    acc += bvec[t];
    hout[d * HD + t] = fmaxf(acc, 0.0f);
}

__device__ __forceinline__ u64 edge_key(float w, int i, int j) {
    unsigned u = __float_as_uint(w);
    u = (u & 0x80000000u) ? ~u : (u | 0x80000000u);
    int a = i < j ? i : j, b = i < j ? j : i;
    unsigned packed = (unsigned)(a * BN + b);
    return ((u64)u << 20) | (u64)(0xFFFFFu - packed);
}

// scores + FUSED Boruvka round-1 best; float4-staged operands (NO fence, NO merge)
__global__ __launch_bounds__(256) void k_scores(const float* Aa, const float* Cc,
                                                const float* Ws2, const float* bs2v,
                                                float* S, u64* best) {
    int bid = blockIdx.x;
    int bi = 0, rem = bid;
    while (rem >= 16 - bi) { rem -= 16 - bi; bi++; }
    int bj = bi + rem;
    __shared__ float As[64][68];
    __shared__ float Cs[64][68];
    __shared__ float w2[HD];
    __shared__ u64 rmax[64], cmax[64];
    int tid = threadIdx.x;
    int R = bi * 64, Cb = bj * 64;
    if (tid < HD) w2[tid] = Ws2[tid];
    if (tid < 64) { rmax[tid] = 0ull; cmax[tid] = 0ull; }
    int tx = tid & 15, ty = tid >> 4;
    float acc[4][4] = {};
    for (int half = 0; half < 2; half++) {
        int k0 = half * 64;
        __syncthreads();
        for (int f = tid; f < 1024; f += 256) {
            int row = f >> 4, kk4 = (f & 15) * 4;
            float4 a = *(const float4*)&Aa[(R + row) * HD + k0 + kk4];
            float4 c = *(const float4*)&Cc[(Cb + row) * HD + k0 + kk4];
            As[kk4 + 0][row] = a.x; As[kk4 + 1][row] = a.y;
            As[kk4 + 2][row] = a.z; As[kk4 + 3][row] = a.w;
            Cs[kk4 + 0][row] = c.x; Cs[kk4 + 1][row] = c.y;
            Cs[kk4 + 2][row] = c.z; Cs[kk4 + 3][row] = c.w;
        }
        __syncthreads();
        for (int kk = 0; kk < 64; kk++) {
            float4 av = *(const float4*)&As[kk][ty * 4];
            float4 cv = *(const float4*)&Cs[kk][tx * 4];
            float wk = w2[k0 + kk];
            float ar[4] = {av.x, av.y, av.z, av.w};
            float cr[4] = {cv.x, cv.y, cv.z, cv.w};
#pragma unroll
            for (int r = 0; r < 4; r++)
#pragma unroll
                for (int q = 0; q < 4; q++) {
                    float tv = fmaxf(ar[r] + cr[q], 0.0f);
                    acc[r][q] = fmaf(tv, wk, acc[r][q]);
                }
        }
    }
    float b2 = bs2v[0];
    u64 rloc[4] = {0ull, 0ull, 0ull, 0ull};
    u64 cloc[4] = {0ull, 0ull, 0ull, 0ull};
#pragma unroll
    for (int r = 0; r < 4; r++)
#pragma unroll
        for (int q = 0; q < 4; q++) {
            int gr = R + ty * 4 + r, gc = Cb + tx * 4 + q;
            float v = acc[r][q] + b2;
            if (gr < gc) {
                S[gr * BN + gc] = v;
                S[gc * BN + gr] = v;
                u64 key = edge_key(v, gr, gc);
                if (key > rloc[r]) rloc[r] = key;
                if (key > cloc[q]) cloc[q] = key;
            } else if (gr == gc) S[gr * BN + gc] = 0.0f;
        }
#pragma unroll
    for (int r = 0; r < 4; r++) {
        if (rloc[r]) atomicMax(&rmax[ty * 4 + r], rloc[r]);
        if (cloc[r]) atomicMax(&cmax[tx * 4 + r], cloc[r]);
    }
    __syncthreads();
    if (tid < 64) {
        if (rmax[tid]) atomicMax(&best[R + tid], rmax[tid]);
    } else if (tid < 128) {
        if (cmax[tid - 64]) atomicMax(&best[Cb + tid - 64], cmax[tid - 64]);
    }
}

// wave-per-row best-outgoing-edge scan (exact); optional ncomp guard
__global__ __launch_bounds__(256) void k_best(const float* S, const int* comp,
                                              u64* best, const int* mstcnt,
                                              const int* ncompG, int ncGuard) {
    if (*mstcnt >= BN - 1) return;
    if (ncGuard && *ncompG <= NC) return;
    int lane = threadIdx.x & 63;
    int i = blockIdx.x * 4 + (threadIdx.x >> 6);
    int ci = comp[i];
    const float* Srow = S + (size_t)i * BN;
    u64 loc = 0ull;
#pragma unroll 4
    for (int j = lane; j < BN; j += 64)
        if (comp[j] != ci) {
            u64 key = edge_key(Srow[j], i, j);
            if (key > loc) loc = key;
        }
#pragma unroll
    for (int off = 32; off > 0; off >>= 1) {
        u64 o = __shfl_xor(loc, off);
        if (o > loc) loc = o;
    }
    if (lane == 0 && loc) atomicMax(&best[ci], loc);
}

// round-1 merge: comp=identity; alternating-buffer doubling (1 barrier/iter)
__global__ __launch_bounds__(1024) void k_merge1(u64* best, int* comp, u64* mst, int* mstcnt) {
    __shared__ int pa[BN], pb[BN];
    int c = threadIdx.x;
    u64 e = best[c];
    unsigned packed = 0xFFFFFu - (unsigned)(e & 0xFFFFFu);
    int a = packed >> 10, b = packed & 1023;
    int t = (a == c) ? b : a;
    pa[c] = t;
    __syncthreads();
    bool mutual = (pa[t] == c);
    int p0 = pa[c];
    if (mutual && c < t) p0 = c;
    __syncthreads();
    pa[c] = p0;
    __syncthreads();
    if (!(mutual && c > t)) {
        int idx = atomicAdd(mstcnt, 1);
        mst[idx] = e;
    }
    int* A = pa;
    int* B = pb;
    for (int it = 0; it < 10; it++) {       // even count -> final state in pa
        B[c] = A[A[c]];
        __syncthreads();
        int* tm = A; A = B; B = tm;
    }
    comp[c] = A[c];
    best[c] = 0ull;
}

// generic merge: alternating doubling + ballot dense renumber (emitDense)
__global__ __launch_bounds__(1024) void k_merge(int* comp, u64* best, u64* mst, int* mstcnt,
                                                int* compD, int* ncompG, int emitDense,
                                                int ncGuard) {
    __shared__ int pa[BN], pb[BN];
    __shared__ u64 masksS[16];
    int c = threadIdx.x;
    if (*mstcnt >= BN - 1) return;
    if (ncGuard && *ncompG <= NC) return;
    int myComp = comp[c];
    bool root = (myComp == c);
    u64 e = best[c];
    int t = c;
    if (root && e) {
        unsigned packed = 0xFFFFFu - (unsigned)(e & 0xFFFFFu);
        int a = packed >> 10, b = packed & 1023;
        int ca = comp[a], cb = comp[b];
        t = (ca == c) ? cb : ca;
    }
    pa[c] = (root && e) ? t : c;
    __syncthreads();
    bool mutual = root && e && (pa[t] == c);
    int p0 = pa[c];
    if (mutual && c < t) p0 = c;
    __syncthreads();
    pa[c] = p0;
    __syncthreads();
    if (root && e && !(mutual && c > t)) {
        int idx = atomicAdd(mstcnt, 1);
        mst[idx] = e;
    }
    int* A = pa;
    int* B = pb;
    for (int it = 0; it < 10; it++) {
        B[c] = A[A[c]];
        __syncthreads();
        int* tm = A; A = B; B = tm;
    }
    comp[c] = A[myComp];
    best[c] = 0ull;
    if (!emitDense) return;
    // ballot-based dense renumber: 2 barriers total
    int lane = c & 63, wv = c >> 6;
    u64 m = __ballot(comp[c] == c);
    if (lane == 0) masksS[wv] = m;
    __syncthreads();
    int r = comp[c];
    int chunk = r >> 6;
    int rk = 0;
    for (int k = 0; k < chunk; k++) rk += __popcll(masksS[k]);
    rk += __popcll(masksS[chunk] & ((1ull << (r & 63)) - 1ull));
    compD[c] = rk;
    if (c == 0) {
        int t2 = 0;
        for (int k = 0; k < 16; k++) t2 += __popcll(masksS[k]);
        *ncompG = t2;
    }
}

// fused G+Sp: per-row LDS table -> global atomicMax into sp[c1][c2] (pre-zeroed)
__global__ __launch_bounds__(256) void k_Gsp(const float* S, const int* compD,
                                             const int* mstcnt, u64* spG) {
    if (*mstcnt >= BN - 1) return;
    __shared__ u64 t[NC];
    int tid = threadIdx.x;
    int i = blockIdx.x;
    int ci = compD[i];
    if (tid < NC) t[tid] = 0ull;
    __syncthreads();
    const float* Srow = S + (size_t)i * BN;
#pragma unroll 2
    for (int j = tid; j < BN; j += 256) {
        int cj = compD[j];
        if (j != i && cj != ci) atomicMax(&t[cj], edge_key(Srow[j], i, j));
    }
    __syncthreads();
    if (tid < NC && t[tid]) atomicMax(&spG[(size_t)ci * NC + tid], t[tid]);
}

struct FinSm {
    union {
        u64 sp[NC][NC];
        u64 sk[BN];
    } u;
    int cnd[BN];
    int ccomp[NC], cpa[NC], cpb[NC];
    u64 cbest[NC];
    int lcnt;
};

// remaining Boruvka rounds on the contracted (<=128 node) graph + finale
__global__ __launch_bounds__(1024) void k_mstfin(const u64* spG, const int* compD,
                                                 const int* ncompG, const int* mstcntG,
                                                 u64* mstG, float* out, int* pairs) {
    __shared__ FinSm sm;
    int c = threadIdx.x;
    int total = *mstcntG;
    if (total < BN - 1) {
        int nc = *ncompG;
        for (int idx = c; idx < NC * NC; idx += 1024) ((u64*)sm.u.sp)[idx] = spG[idx];
        sm.cnd[c] = compD[c];
        if (c < NC) { sm.ccomp[c] = c; sm.cbest[c] = 0ull; }
        if (c == 0) sm.lcnt = 0;
        __syncthreads();
        for (int rr = 0; rr < 8 && total < BN - 1; rr++) {
            if (c < nc) {
                int g = sm.ccomp[c];
                u64 m = 0ull;
                for (int c2 = 0; c2 < nc; c2++)
                    if (sm.ccomp[c2] != g) {
                        u64 v = sm.u.sp[c][c2];
                        if (v > m) m = v;
                    }
                if (m) atomicMax(&sm.cbest[g], m);
            }
            __syncthreads();
            if (c < nc) {
                bool root = (sm.ccomp[c] == c);
                u64 e = sm.cbest[c];
                int t2 = c;
                if (root && e) {
                    unsigned packed = 0xFFFFFu - (unsigned)(e & 0xFFFFFu);
                    int a = packed >> 10, b = packed & 1023;
                    int ga = sm.ccomp[sm.cnd[a]], gb = sm.ccomp[sm.cnd[b]];
                    t2 = (ga == c) ? gb : ga;
                }
                sm.cpa[c] = (root && e) ? t2 : c;
            }
            __syncthreads();
            if (c < nc) {
                bool root = (sm.ccomp[c] == c);
                u64 e = sm.cbest[c];
                int t2 = sm.cpa[c];
                bool mutual = root && e && (sm.cpa[t2] == c);
                int p0 = sm.cpa[c];
                if (mutual && c < t2) p0 = c;
                sm.cpb[c] = p0;
                if (root && e && !(mutual && c > t2)) {
                    int idx = total + atomicAdd(&sm.lcnt, 1);
                    mstG[idx] = e;
                }
            }
            __syncthreads();
            if (c < nc) sm.cpa[c] = sm.cpb[c];
            __syncthreads();
            {
                int* X = sm.cpa;
                int* Y = sm.cpb;
                for (int it = 0; it < 8; it++) {   // even count -> final state in cpa
                    if (c < nc) Y[c] = X[X[c]];
                    __syncthreads();
                    int* tm = X; X = Y; Y = tm;
                }
            }
            if (c < nc) {
                sm.ccomp[c] = sm.cpa[sm.ccomp[c]];
                sm.cbest[c] = 0ull;
            }
            __syncthreads();
            int added = sm.lcnt;
            __syncthreads();
            total += added;
            if (c == 0) sm.lcnt = 0;
            __syncthreads();
        }
    }
    __syncthreads();
    sm.u.sk[c] = (c < BN - 1) ? mstG[c] : 0ull;
    __syncthreads();
    if (c < BN - 1) {
        u64 mykey = sm.u.sk[c];
        int rk = 0;
        for (int f = 0; f < BN - 1; f++) rk += (sm.u.sk[f] > mykey) ? 1 : 0;
        unsigned packed = 0xFFFFFu - (unsigned)(mykey & 0xFFFFFu);
        int i = packed >> 10, j2 = packed & 1023;
        out[2 * rk] = (float)i;
        out[2 * rk + 1] = (float)j2;
        out[2046 + 2 * rk] = (float)j2;
        out[2046 + 2 * rk + 1] = (float)i;
        pairs[2 * rk] = i;
        pairs[2 * rk + 1] = j2;
    }
}

// 8 edges/block: W loads amortized 8x, 4 independent fma chains/thread
__global__ __launch_bounds__(256) void k_gamma8(const float* h, const int* pairs,
                                                const float* Wg1, const float* bg1,
                                                const float* Wg2, const float* bg2, float* out) {
    __shared__ float hp[EGR][2 * HD];
    __shared__ float z1[EGR][HD];
    int tid = threadIdx.x;
    int e0 = blockIdx.x * EGR;
    for (int idx = tid; idx < EGR * 2 * HD; idx += 256) {
        int eo = idx >> 8;
        int k = idx & 255;
        int e = e0 + eo;
        if (e < BN - 1) {
            int node = (k < HD) ? pairs[2 * e] : pairs[2 * e + 1];
            hp[eo][k] = h[node * HD + (k & 127)];
        }
    }
    __syncthreads();
    {
        int c = tid & 127, eg = tid >> 7;
        float b = bg1[c];
        float a0 = b, a1 = b, a2 = b, a3 = b;
#pragma unroll 4
        for (int k = 0; k < 2 * HD; k++) {
            float w = Wg1[k * HD + c];
            a0 = fmaf(hp[eg * 4 + 0][k], w, a0);
            a1 = fmaf(hp[eg * 4 + 1][k], w, a1);
            a2 = fmaf(hp[eg * 4 + 2][k], w, a2);
            a3 = fmaf(hp[eg * 4 + 3][k], w, a3);
        }
        z1[eg * 4 + 0][c] = fmaxf(a0, 0.0f);
        z1[eg * 4 + 1][c] = fmaxf(a1, 0.0f);
        z1[eg * 4 + 2][c] = fmaxf(a2, 0.0f);
        z1[eg * 4 + 3][c] = fmaxf(a3, 0.0f);
    }
    __syncthreads();
    {
        int co = tid & 63, eh = tid >> 6;
        float b = bg2[co];
        float g0 = b, g1 = b;
#pragma unroll 4
        for (int k = 0; k < HD; k++) {
            float w = Wg2[k * DIN + co];
            g0 = fmaf(z1[eh * 2 + 0][k], w, g0);
            g1 = fmaf(z1[eh * 2 + 1][k], w, g1);
        }
        int ea = e0 + eh * 2, eb = ea + 1;
        if (ea < BN - 1) out[4092 + ea * DIN + co] = tanhf(g0);
        if (eb < BN - 1) out[4092 + eb * DIN + co] = tanhf(g1);
    }
}

extern "C" void kernel_launch(void* const* d_in, const int* in_sizes, int n_in,
                              void* d_out, int out_size, void* d_ws, size_t ws_size,
                              hipStream_t stream) {
    const float* mu  = (const float*)d_in[0];
    const int*   ei  = (const int*)d_in[1];
    const float* W1  = (const float*)d_in[2];
    const float* b1  = (const float*)d_in[3];
    const float* W2  = (const float*)d_in[4];
    const float* b2  = (const float*)d_in[5];
    const float* Ws1 = (const float*)d_in[6];
    const float* bs1 = (const float*)d_in[7];
    const float* Ws2 = (const float*)d_in[8];
    const float* bs2 = (const float*)d_in[9];
    const float* Wg1 = (const float*)d_in[10];
    const float* bg1 = (const float*)d_in[11];
    const float* Wg2 = (const float*)d_in[12];
    const float* bg2 = (const float*)d_in[13];
    float* out = (float*)d_out;

    const int* src = ei;
    const int* dst = ei + EN;

    char* ws = (char*)d_ws;
    int*   slots = (int*)(ws);                      // 256 KiB (aliases S, dead pre-scores)
    float* S     = (float*)(ws);                    // 4 MiB, born at k_scores
    float* xw    = (float*)(ws + 4194304);
    float* h1    = (float*)(ws + 4718592);
    float* h2    = (float*)(ws + 5242880);
    float* Aa    = (float*)(ws + 5767168);
    float* Cc    = (float*)(ws + 6291456);
    // contiguous memset region: [cnt | best | mstcnt | spG] = 147456 B
    int*   cnt   = (int*)(ws + 6815744);
    u64*   best  = (u64*)(ws + 6819840);
    int*   mstcnt = (int*)(ws + 6828032);
    u64*   spG   = (u64*)(ws + 6832128);
    // end memset region
    int*   comp  = (int*)(ws + 6963200);
    u64*   mstG  = (u64*)(ws + 6967296);
    int*   pairs = (int*)(ws + 6975488);
    int*   compD = (int*)(ws + 6983680);
    int*   ncomp = (int*)(ws + 6987776);
    float* dinv  = (float*)(ws + 6991872);

    hipMemsetAsync(ws + 6815744, 0, 147456, stream);

    k_fill<<<EN / 256, 256, 0, stream>>>(dst, cnt, slots);
    k_finmm1<<<260, 256, 0, stream>>>(slots, cnt, dinv, mu, W1, xw);
    k_gather<<<BN, HD, 0, stream>>>(xw, b1, src, slots, cnt, dinv, h1);
    k_mm128<<<BN / MMR4, 256, 0, stream>>>(h1, W2, xw);
    k_gather<<<BN, HD, 0, stream>>>(xw, b2, src, slots, cnt, dinv, h2);

    k_mmAC<<<BN / MMR4, 256, 0, stream>>>(h2, Ws1, bs1, Aa, Cc);

    k_scores<<<136, 256, 0, stream>>>(Aa, Cc, Ws2, bs2, S, best);

    k_merge1<<<1, 1024, 0, stream>>>(best, comp, mstG, mstcnt);
    k_best<<<BN / 4, 256, 0, stream>>>(S, comp, best, mstcnt, ncomp, 0);
    k_merge<<<1, 1024, 0, stream>>>(comp, best, mstG, mstcnt, compD, ncomp, 1, 0);
    k_best<<<BN / 4, 256, 0, stream>>>(S, comp, best, mstcnt, ncomp, 1);
    k_merge<<<1, 1024, 0, stream>>>(comp, best, mstG, mstcnt, compD, ncomp, 1, 1);

    k_Gsp<<<BN, 256, 0, stream>>>(S, compD, mstcnt, spG);
    k_mstfin<<<1, 1024, 0, stream>>>(spG, compD, ncomp, mstcnt, mstG, out, pairs);

    k_gamma8<<<(BN - 1 + EGR - 1) / EGR, 256, 0, stream>>>(h2, pairs, Wg1, bg1, Wg2, bg2, out);
}

// Round 18
// 152.821 us; speedup vs baseline: 1.2318x; 1.0010x over previous
//
#include <hip/hip_runtime.h>
#include <hip/hip_bf16.h>
#include <math.h>

#define BN 1024
#define DIN 64
#define HD 128
#define EN 8192
#define SLOTS_STRIDE 64
#define MMR4 4
#define EGR 8
#define NC 128

typedef unsigned long long u64;

// zero the [cnt | best | mstcnt | spG] region: 147456 B = 9216 float4 (36 blocks x 256)
__global__ __launch_bounds__(256) void k_zero(float4* p) {
    int i = blockIdx.x * 256 + threadIdx.x;
    p[i] = make_float4(0.0f, 0.0f, 0.0f, 0.0f);
}

__global__ void k_fill(const int* dst, int* cnt, int* slots) {
    int e = blockIdx.x * blockDim.x + threadIdx.x;
    if (e < EN) {
        int d = dst[e];
        int p = atomicAdd(&cnt[d], 1);
        if (p < SLOTS_STRIDE) slots[d * SLOTS_STRIDE + p] = e;
    }
}

// FUSED: blocks 0..3 = per-node CSR sort + dinv; blocks 4..259 = mm1 (xw = mu @ W1)
struct FinMmSm {
    union {
        int buf[256][65];
        struct { float Wl[DIN * HD]; float xr[MMR4][DIN]; } m;
    } u;
};
__global__ __launch_bounds__(256) void k_finmm1(int* slots, const int* cnt, float* dinv,
                                                const float* mu, const float* W1, float* xw) {
    __shared__ FinMmSm sm;
    int tid = threadIdx.x;
    if (blockIdx.x < 4) {
        int t = blockIdx.x * 256 + tid;
        int n = cnt[t];
        if (n > SLOTS_STRIDE) n = SLOTS_STRIDE;
        for (int k = 0; k < n; k++) sm.u.buf[tid][k] = slots[t * SLOTS_STRIDE + k];
        for (int k = 1; k < n; k++) {
            int v = sm.u.buf[tid][k];
            int q = k - 1;
            while (q >= 0 && sm.u.buf[tid][q] > v) { sm.u.buf[tid][q + 1] = sm.u.buf[tid][q]; q--; }
            sm.u.buf[tid][q + 1] = v;
        }
        for (int k = 0; k < n; k++) slots[t * SLOTS_STRIDE + k] = sm.u.buf[tid][k];
        dinv[t] = 1.0f / sqrtf(fmaxf((float)(n + 1), 1e-12f));
    } else {
        int r0 = (blockIdx.x - 4) * MMR4;
        for (int idx = tid; idx < DIN * HD / 4; idx += 256)
            ((float4*)sm.u.m.Wl)[idx] = ((const float4*)W1)[idx];
        for (int idx = tid; idx < MMR4 * DIN / 4; idx += 256) {
            float4 v = ((const float4*)(mu + r0 * DIN))[idx];
            int row = (idx * 4) / DIN, col = (idx * 4) % DIN;
            sm.u.m.xr[row][col] = v.x; sm.u.m.xr[row][col + 1] = v.y;
            sm.u.m.xr[row][col + 2] = v.z; sm.u.m.xr[row][col + 3] = v.w;
        }
        __syncthreads();
        int col = tid & 127, half = tid >> 7;
        float a0 = 0.0f, a1 = 0.0f;
#pragma unroll 4
        for (int k = 0; k < DIN; k++) {
            float w = sm.u.m.Wl[k * HD + col];
            a0 = fmaf(sm.u.m.xr[half * 2 + 0][k], w, a0);
            a1 = fmaf(sm.u.m.xr[half * 2 + 1][k], w, a1);
        }
        xw[(r0 + half * 2 + 0) * HD + col] = a0;
        xw[(r0 + half * 2 + 1) * HD + col] = a1;
    }
}

// mm with LDS-staged W (K=128): 4 rows/block, 256 threads
__global__ __launch_bounds__(256) void k_mm128(const float* x, const float* W, float* out) {
    __shared__ float Wl[HD * HD];
    __shared__ float xr[MMR4][HD];
    int tid = threadIdx.x;
    int r0 = blockIdx.x * MMR4;
    for (int idx = tid; idx < HD * HD / 4; idx += 256)
        ((float4*)Wl)[idx] = ((const float4*)W)[idx];
    for (int idx = tid; idx < MMR4 * HD / 4; idx += 256) {
        float4 v = ((const float4*)(x + r0 * HD))[idx];
        int row = idx >> 5, col = (idx & 31) * 4;
        xr[row][col] = v.x; xr[row][col + 1] = v.y; xr[row][col + 2] = v.z; xr[row][col + 3] = v.w;
    }
    __syncthreads();
    int col = tid & 127, half = tid >> 7;
    float a0 = 0.0f, a1 = 0.0f;
#pragma unroll 4
    for (int k = 0; k < HD; k++) {
        float w = Wl[k * HD + col];
        a0 = fmaf(xr[half * 2 + 0][k], w, a0);
        a1 = fmaf(xr[half * 2 + 1][k], w, a1);
    }
    out[(r0 + half * 2 + 0) * HD + col] = a0;
    out[(r0 + half * 2 + 1) * HD + col] = a1;
}

// fused Aa/Cc with full Ws1 (128 KB) staged in LDS
__global__ __launch_bounds__(256) void k_mmAC(const float* h, const float* Ws1, const float* bs1,
                                              float* Aa, float* Cc) {
    __shared__ float Wl[2 * HD * HD];
    __shared__ float xr[MMR4][HD];
    int tid = threadIdx.x;
    int r0 = blockIdx.x * MMR4;
    for (int idx = tid; idx < 2 * HD * HD / 4; idx += 256)
        ((float4*)Wl)[idx] = ((const float4*)Ws1)[idx];
    for (int idx = tid; idx < MMR4 * HD / 4; idx += 256) {
        float4 v = ((const float4*)(h + r0 * HD))[idx];
        int row = idx >> 5, col = (idx & 31) * 4;
        xr[row][col] = v.x; xr[row][col + 1] = v.y; xr[row][col + 2] = v.z; xr[row][col + 3] = v.w;
    }
    __syncthreads();
    int col = tid & 127, half = tid >> 7;
    float bc = bs1[col];
    float A0 = 0.0f, A1 = 0.0f, C0 = bc, C1 = bc;
#pragma unroll 2
    for (int k = 0; k < HD; k++) {
        float wa = Wl[k * HD + col];
        float wc = Wl[(HD + k) * HD + col];
        A0 = fmaf(xr[half * 2 + 0][k], wa, A0);
        A1 = fmaf(xr[half * 2 + 1][k], wa, A1);
        C0 = fmaf(xr[half * 2 + 0][k], wc, C0);
        C1 = fmaf(xr[half * 2 + 1][k], wc, C1);
    }
    Aa[(r0 + half * 2 + 0) * HD + col] = A0;
    Aa[(r0 + half * 2 + 1) * HD + col] = A1;
    Cc[(r0 + half * 2 + 0) * HD + col] = C0;
    Cc[(r0 + half * 2 + 1) * HD + col] = C1;
}

// GCN gather: parallel edge-list prefetch + unrolled accumulate
__global__ __launch_bounds__(128) void k_gather(const float* xw, const float* bvec, const int* src,
                                                const int* slots, const int* cnt,
                                                const float* dinv, float* hout) {
    __shared__ int sn_s[SLOTS_STRIDE];
    __shared__ float w_s[SLOTS_STRIDE];
    int d = blockIdx.x, t = threadIdx.x;
    float dd = dinv[d];
    int n = cnt[d];
    if (n > SLOTS_STRIDE) n = SLOTS_STRIDE;
    if (t < n) {
        int e = slots[d * SLOTS_STRIDE + t];
        int sn = src[e];
        sn_s[t] = sn;
        w_s[t] = dinv[sn] * dd;
    }
    __syncthreads();
    float acc = 0.0f;
#pragma unroll 4
    for (int s = 0; s < n; s++)
        acc = fmaf(xw[sn_s[s] * HD + t], w_s[s], acc);
    acc = fmaf(xw[d * HD + t], dd * dd, acc);
    acc += bvec[t];
    hout[d * HD + t] = fmaxf(acc, 0.0f);
}

__device__ __forceinline__ u64 edge_key(float w, int i, int j) {
    unsigned u = __float_as_uint(w);
    u = (u & 0x80000000u) ? ~u : (u | 0x80000000u);
    int a = i < j ? i : j, b = i < j ? j : i;
    unsigned packed = (unsigned)(a * BN + b);
    return ((u64)u << 20) | (u64)(0xFFFFFu - packed);
}

// scores + FUSED Boruvka round-1 best; float4-staged operands
__global__ __launch_bounds__(256) void k_scores(const float* Aa, const float* Cc,
                                                const float* Ws2, const float* bs2v,
                                                float* S, u64* best) {
    int bid = blockIdx.x;
    int bi = 0, rem = bid;
    while (rem >= 16 - bi) { rem -= 16 - bi; bi++; }
    int bj = bi + rem;
    __shared__ float As[64][68];
    __shared__ float Cs[64][68];
    __shared__ float w2[HD];
    __shared__ u64 rmax[64], cmax[64];
    int tid = threadIdx.x;
    int R = bi * 64, Cb = bj * 64;
    if (tid < HD) w2[tid] = Ws2[tid];
    if (tid < 64) { rmax[tid] = 0ull; cmax[tid] = 0ull; }
    int tx = tid & 15, ty = tid >> 4;
    float acc[4][4] = {};
    for (int half = 0; half < 2; half++) {
        int k0 = half * 64;
        __syncthreads();
        for (int f = tid; f < 1024; f += 256) {
            int row = f >> 4, kk4 = (f & 15) * 4;
            float4 a = *(const float4*)&Aa[(R + row) * HD + k0 + kk4];
            float4 c = *(const float4*)&Cc[(Cb + row) * HD + k0 + kk4];
            As[kk4 + 0][row] = a.x; As[kk4 + 1][row] = a.y;
            As[kk4 + 2][row] = a.z; As[kk4 + 3][row] = a.w;
            Cs[kk4 + 0][row] = c.x; Cs[kk4 + 1][row] = c.y;
            Cs[kk4 + 2][row] = c.z; Cs[kk4 + 3][row] = c.w;
        }
        __syncthreads();
        for (int kk = 0; kk < 64; kk++) {
            float4 av = *(const float4*)&As[kk][ty * 4];
            float4 cv = *(const float4*)&Cs[kk][tx * 4];
            float wk = w2[k0 + kk];
            float ar[4] = {av.x, av.y, av.z, av.w};
            float cr[4] = {cv.x, cv.y, cv.z, cv.w};
#pragma unroll
            for (int r = 0; r < 4; r++)
#pragma unroll
                for (int q = 0; q < 4; q++) {
                    float tv = fmaxf(ar[r] + cr[q], 0.0f);
                    acc[r][q] = fmaf(tv, wk, acc[r][q]);
                }
        }
    }
    float b2 = bs2v[0];
    u64 rloc[4] = {0ull, 0ull, 0ull, 0ull};
    u64 cloc[4] = {0ull, 0ull, 0ull, 0ull};
#pragma unroll
    for (int r = 0; r < 4; r++)
#pragma unroll
        for (int q = 0; q < 4; q++) {
            int gr = R + ty * 4 + r, gc = Cb + tx * 4 + q;
            float v = acc[r][q] + b2;
            if (gr < gc) {
                S[gr * BN + gc] = v;
                S[gc * BN + gr] = v;
                u64 key = edge_key(v, gr, gc);
                if (key > rloc[r]) rloc[r] = key;
                if (key > cloc[q]) cloc[q] = key;
            } else if (gr == gc) S[gr * BN + gc] = 0.0f;
        }
#pragma unroll
    for (int r = 0; r < 4; r++) {
        if (rloc[r]) atomicMax(&rmax[ty * 4 + r], rloc[r]);
        if (cloc[r]) atomicMax(&cmax[tx * 4 + r], cloc[r]);
    }
    __syncthreads();
    if (tid < 64) {
        if (rmax[tid]) atomicMax(&best[R + tid], rmax[tid]);
    } else if (tid < 128) {
        if (cmax[tid - 64]) atomicMax(&best[Cb + tid - 64], cmax[tid - 64]);
    }
}

// wave-per-row best-outgoing-edge scan (exact); optional ncomp guard
__global__ __launch_bounds__(256) void k_best(const float* S, const int* comp,
                                              u64* best, const int* mstcnt,
                                              const int* ncompG, int ncGuard) {
    if (*mstcnt >= BN - 1) return;
    if (ncGuard && *ncompG <= NC) return;
    int lane = threadIdx.x & 63;
    int i = blockIdx.x * 4 + (threadIdx.x >> 6);
    int ci = comp[i];
    const float* Srow = S + (size_t)i * BN;
    u64 loc = 0ull;
#pragma unroll 4
    for (int j = lane; j < BN; j += 64)
        if (comp[j] != ci) {
            u64 key = edge_key(Srow[j], i, j);
            if (key > loc) loc = key;
        }
#pragma unroll
    for (int off = 32; off > 0; off >>= 1) {
        u64 o = __shfl_xor(loc, off);
        if (o > loc) loc = o;
    }
    if (lane == 0 && loc) atomicMax(&best[ci], loc);
}

// round-1 merge: comp=identity; alternating-buffer doubling (1 barrier/iter)
__global__ __launch_bounds__(1024) void k_merge1(u64* best, int* comp, u64* mst, int* mstcnt) {
    __shared__ int pa[BN], pb[BN];
    int c = threadIdx.x;
    u64 e = best[c];
    unsigned packed = 0xFFFFFu - (unsigned)(e & 0xFFFFFu);
    int a = packed >> 10, b = packed & 1023;
    int t = (a == c) ? b : a;
    pa[c] = t;
    __syncthreads();
    bool mutual = (pa[t] == c);
    int p0 = pa[c];
    if (mutual && c < t) p0 = c;
    __syncthreads();
    pa[c] = p0;
    __syncthreads();
    if (!(mutual && c > t)) {
        int idx = atomicAdd(mstcnt, 1);
        mst[idx] = e;
    }
    int* A = pa;
    int* B = pb;
    for (int it = 0; it < 10; it++) {       // even count -> final state in pa
        B[c] = A[A[c]];
        __syncthreads();
        int* tm = A; A = B; B = tm;
    }
    comp[c] = A[c];
    best[c] = 0ull;
}

// generic merge: alternating doubling + ballot dense renumber (emitDense)
__global__ __launch_bounds__(1024) void k_merge(int* comp, u64* best, u64* mst, int* mstcnt,
                                                int* compD, int* ncompG, int emitDense,
                                                int ncGuard) {
    __shared__ int pa[BN], pb[BN];
    __shared__ u64 masksS[16];
    int c = threadIdx.x;
    if (*mstcnt >= BN - 1) return;
    if (ncGuard && *ncompG <= NC) return;
    int myComp = comp[c];
    bool root = (myComp == c);
    u64 e = best[c];
    int t = c;
    if (root && e) {
        unsigned packed = 0xFFFFFu - (unsigned)(e & 0xFFFFFu);
        int a = packed >> 10, b = packed & 1023;
        int ca = comp[a], cb = comp[b];
        t = (ca == c) ? cb : ca;
    }
    pa[c] = (root && e) ? t : c;
    __syncthreads();
    bool mutual = root && e && (pa[t] == c);
    int p0 = pa[c];
    if (mutual && c < t) p0 = c;
    __syncthreads();
    pa[c] = p0;
    __syncthreads();
    if (root && e && !(mutual && c > t)) {
        int idx = atomicAdd(mstcnt, 1);
        mst[idx] = e;
    }
    int* A = pa;
    int* B = pb;
    for (int it = 0; it < 10; it++) {
        B[c] = A[A[c]];
        __syncthreads();
        int* tm = A; A = B; B = tm;
    }
    comp[c] = A[myComp];
    best[c] = 0ull;
    if (!emitDense) return;
    // ballot-based dense renumber: 2 barriers total
    int lane = c & 63, wv = c >> 6;
    u64 m = __ballot(comp[c] == c);
    if (lane == 0) masksS[wv] = m;
    __syncthreads();
    int r = comp[c];
    int chunk = r >> 6;
    int rk = 0;
    for (int k = 0; k < chunk; k++) rk += __popcll(masksS[k]);
    rk += __popcll(masksS[chunk] & ((1ull << (r & 63)) - 1ull));
    compD[c] = rk;
    if (c == 0) {
        int t2 = 0;
        for (int k = 0; k < 16; k++) t2 += __popcll(masksS[k]);
        *ncompG = t2;
    }
}

// fused G+Sp: per-row LDS table -> global atomicMax into sp[c1][c2] (pre-zeroed)
__global__ __launch_bounds__(256) void k_Gsp(const float* S, const int* compD,
                                             const int* mstcnt, u64* spG) {
    if (*mstcnt >= BN - 1) return;
    __shared__ u64 t[NC];
    int tid = threadIdx.x;
    int i = blockIdx.x;
    int ci = compD[i];
    if (tid < NC) t[tid] = 0ull;
    __syncthreads();
    const float* Srow = S + (size_t)i * BN;
#pragma unroll 2
    for (int j = tid; j < BN; j += 256) {
        int cj = compD[j];
        if (j != i && cj != ci) atomicMax(&t[cj], edge_key(Srow[j], i, j));
    }
    __syncthreads();
    if (tid < NC && t[tid]) atomicMax(&spG[(size_t)ci * NC + tid], t[tid]);
}

struct FinSm {
    union {
        u64 sp[NC][NC];
        u64 sk[BN];
    } u;
    int cnd[BN];
    int ccomp[NC], cpa[NC], cpb[NC];
    u64 cbest[NC];
    int lcnt;
};

// remaining Boruvka rounds on the contracted (<=128 node) graph + finale
__global__ __launch_bounds__(1024) void k_mstfin(const u64* spG, const int* compD,
                                                 const int* ncompG, const int* mstcntG,
                                                 u64* mstG, float* out, int* pairs) {
    __shared__ FinSm sm;
    int c = threadIdx.x;
    int total = *mstcntG;
    if (total < BN - 1) {
        int nc = *ncompG;
        for (int idx = c; idx < NC * NC; idx += 1024) ((u64*)sm.u.sp)[idx] = spG[idx];
        sm.cnd[c] = compD[c];
        if (c < NC) { sm.ccomp[c] = c; sm.cbest[c] = 0ull; }
        if (c == 0) sm.lcnt = 0;
        __syncthreads();
        for (int rr = 0; rr < 8 && total < BN - 1; rr++) {
            if (c < nc) {
                int g = sm.ccomp[c];
                u64 m = 0ull;
                for (int c2 = 0; c2 < nc; c2++)
                    if (sm.ccomp[c2] != g) {
                        u64 v = sm.u.sp[c][c2];
                        if (v > m) m = v;
                    }
                if (m) atomicMax(&sm.cbest[g], m);
            }
            __syncthreads();
            if (c < nc) {
                bool root = (sm.ccomp[c] == c);
                u64 e = sm.cbest[c];
                int t2 = c;
                if (root && e) {
                    unsigned packed = 0xFFFFFu - (unsigned)(e & 0xFFFFFu);
                    int a = packed >> 10, b = packed & 1023;
                    int ga = sm.ccomp[sm.cnd[a]], gb = sm.ccomp[sm.cnd[b]];
                    t2 = (ga == c) ? gb : ga;
                }
                sm.cpa[c] = (root && e) ? t2 : c;
            }
            __syncthreads();
            if (c < nc) {
                bool root = (sm.ccomp[c] == c);
                u64 e = sm.cbest[c];
                int t2 = sm.cpa[c];
                bool mutual = root && e && (sm.cpa[t2] == c);
                int p0 = sm.cpa[c];
                if (mutual && c < t2) p0 = c;
                sm.cpb[c] = p0;
                if (root && e && !(mutual && c > t2)) {
                    int idx = total + atomicAdd(&sm.lcnt, 1);
                    mstG[idx] = e;
                }
            }
            __syncthreads();
            if (c < nc) sm.cpa[c] = sm.cpb[c];
            __syncthreads();
            {
                int* X = sm.cpa;
                int* Y = sm.cpb;
                for (int it = 0; it < 8; it++) {   // even count -> final state in cpa
                    if (c < nc) Y[c] = X[X[c]];
                    __syncthreads();
                    int* tm = X; X = Y; Y = tm;
                }
            }
            if (c < nc) {
                sm.ccomp[c] = sm.cpa[sm.ccomp[c]];
                sm.cbest[c] = 0ull;
            }
            __syncthreads();
            int added = sm.lcnt;
            __syncthreads();
            total += added;
            if (c == 0) sm.lcnt = 0;
            __syncthreads();
        }
    }
    __syncthreads();
    sm.u.sk[c] = (c < BN - 1) ? mstG[c] : 0ull;
    __syncthreads();
    if (c < BN - 1) {
        u64 mykey = sm.u.sk[c];
        int rk = 0;
        for (int f = 0; f < BN - 1; f++) rk += (sm.u.sk[f] > mykey) ? 1 : 0;
        unsigned packed = 0xFFFFFu - (unsigned)(mykey & 0xFFFFFu);
        int i = packed >> 10, j2 = packed & 1023;
        out[2 * rk] = (float)i;
        out[2 * rk + 1] = (float)j2;
        out[2046 + 2 * rk] = (float)j2;
        out[2046 + 2 * rk + 1] = (float)i;
        pairs[2 * rk] = i;
        pairs[2 * rk + 1] = j2;
    }
}

// 8 edges/block: W loads amortized 8x, 4 independent fma chains/thread
__global__ __launch_bounds__(256) void k_gamma8(const float* h, const int* pairs,
                                                const float* Wg1, const float* bg1,
                                                const float* Wg2, const float* bg2, float* out) {
    __shared__ float hp[EGR][2 * HD];
    __shared__ float z1[EGR][HD];
    int tid = threadIdx.x;
    int e0 = blockIdx.x * EGR;
    for (int idx = tid; idx < EGR * 2 * HD; idx += 256) {
        int eo = idx >> 8;
        int k = idx & 255;
        int e = e0 + eo;
        if (e < BN - 1) {
            int node = (k < HD) ? pairs[2 * e] : pairs[2 * e + 1];
            hp[eo][k] = h[node * HD + (k & 127)];
        }
    }
    __syncthreads();
    {
        int c = tid & 127, eg = tid >> 7;
        float b = bg1[c];
        float a0 = b, a1 = b, a2 = b, a3 = b;
#pragma unroll 4
        for (int k = 0; k < 2 * HD; k++) {
            float w = Wg1[k * HD + c];
            a0 = fmaf(hp[eg * 4 + 0][k], w, a0);
            a1 = fmaf(hp[eg * 4 + 1][k], w, a1);
            a2 = fmaf(hp[eg * 4 + 2][k], w, a2);
            a3 = fmaf(hp[eg * 4 + 3][k], w, a3);
        }
        z1[eg * 4 + 0][c] = fmaxf(a0, 0.0f);
        z1[eg * 4 + 1][c] = fmaxf(a1, 0.0f);
        z1[eg * 4 + 2][c] = fmaxf(a2, 0.0f);
        z1[eg * 4 + 3][c] = fmaxf(a3, 0.0f);
    }
    __syncthreads();
    {
        int co = tid & 63, eh = tid >> 6;
        float b = bg2[co];
        float g0 = b, g1 = b;
#pragma unroll 4
        for (int k = 0; k < HD; k++) {
            float w = Wg2[k * DIN + co];
            g0 = fmaf(z1[eh * 2 + 0][k], w, g0);
            g1 = fmaf(z1[eh * 2 + 1][k], w, g1);
        }
        int ea = e0 + eh * 2, eb = ea + 1;
        if (ea < BN - 1) out[4092 + ea * DIN + co] = tanhf(g0);
        if (eb < BN - 1) out[4092 + eb * DIN + co] = tanhf(g1);
    }
}

extern "C" void kernel_launch(void* const* d_in, const int* in_sizes, int n_in,
                              void* d_out, int out_size, void* d_ws, size_t ws_size,
                              hipStream_t stream) {
    const float* mu  = (const float*)d_in[0];
    const int*   ei  = (const int*)d_in[1];
    const float* W1  = (const float*)d_in[2];
    const float* b1  = (const float*)d_in[3];
    const float* W2  = (const float*)d_in[4];
    const float* b2  = (const float*)d_in[5];
    const float* Ws1 = (const float*)d_in[6];
    const float* bs1 = (const float*)d_in[7];
    const float* Ws2 = (const float*)d_in[8];
    const float* bs2 = (const float*)d_in[9];
    const float* Wg1 = (const float*)d_in[10];
    const float* bg1 = (const float*)d_in[11];
    const float* Wg2 = (const float*)d_in[12];
    const float* bg2 = (const float*)d_in[13];
    float* out = (float*)d_out;

    const int* src = ei;
    const int* dst = ei + EN;

    char* ws = (char*)d_ws;
    int*   slots = (int*)(ws);                      // 256 KiB (aliases S, dead pre-scores)
    float* S     = (float*)(ws);                    // 4 MiB, born at k_scores
    float* xw    = (float*)(ws + 4194304);
    float* h1    = (float*)(ws + 4718592);
    float* h2    = (float*)(ws + 5242880);
    float* Aa    = (float*)(ws + 5767168);
    float* Cc    = (float*)(ws + 6291456);
    // contiguous zero region: [cnt | best | mstcnt | spG] = 147456 B
    int*   cnt   = (int*)(ws + 6815744);
    u64*   best  = (u64*)(ws + 6819840);
    int*   mstcnt = (int*)(ws + 6828032);
    u64*   spG   = (u64*)(ws + 6832128);
    // end zero region
    int*   comp  = (int*)(ws + 6963200);
    u64*   mstG  = (u64*)(ws + 6967296);
    int*   pairs = (int*)(ws + 6975488);
    int*   compD = (int*)(ws + 6983680);
    int*   ncomp = (int*)(ws + 6987776);
    float* dinv  = (float*)(ws + 6991872);

    k_zero<<<36, 256, 0, stream>>>((float4*)(ws + 6815744));

    k_fill<<<EN / 256, 256, 0, stream>>>(dst, cnt, slots);
    k_finmm1<<<260, 256, 0, stream>>>(slots, cnt, dinv, mu, W1, xw);
    k_gather<<<BN, HD, 0, stream>>>(xw, b1, src, slots, cnt, dinv, h1);
    k_mm128<<<BN / MMR4, 256, 0, stream>>>(h1, W2, xw);
    k_gather<<<BN, HD, 0, stream>>>(xw, b2, src, slots, cnt, dinv, h2);

    k_mmAC<<<BN / MMR4, 256, 0, stream>>>(h2, Ws1, bs1, Aa, Cc);

    k_scores<<<136, 256, 0, stream>>>(Aa, Cc, Ws2, bs2, S, best);

    k_merge1<<<1, 1024, 0, stream>>>(best, comp, mstG, mstcnt);
    k_best<<<BN / 4, 256, 0, stream>>>(S, comp, best, mstcnt, ncomp, 0);
    k_merge<<<1, 1024, 0, stream>>>(comp, best, mstG, mstcnt, compD, ncomp, 1, 0);
    k_best<<<BN / 4, 256, 0, stream>>>(S, comp, best, mstcnt, ncomp, 1);
    k_merge<<<1, 1024, 0, stream>>>(comp, best, mstG, mstcnt, compD, ncomp, 1, 1);

    k_Gsp<<<BN, 256, 0, stream>>>(S, compD, mstcnt, spG);
    k_mstfin<<<1, 1024, 0, stream>>>(spG, compD, ncomp, mstcnt, mstG, out, pairs);

    k_gamma8<<<(BN - 1 + EGR - 1) / EGR, 256, 0, stream>>>(h2, pairs, Wg1, bg1, Wg2, bg2, out);
}

// Round 19
// 152.295 us; speedup vs baseline: 1.2360x; 1.0035x over previous
//
#include <hip/hip_runtime.h>
#include <hip/hip_bf16.h>
#include <math.h>

#define BN 1024
#define DIN 64
#define HD 128
#define EN 8192
#define SLOTS_STRIDE 64
#define MMR4 4
#define EGR 8
#define NC 128

typedef unsigned long long u64;

// zero the [cnt | best | mstcnt | spG] region: 147456 B = 9216 float4 (36 blocks x 256)
__global__ __launch_bounds__(256) void k_zero(float4* p) {
    int i = blockIdx.x * 256 + threadIdx.x;
    p[i] = make_float4(0.0f, 0.0f, 0.0f, 0.0f);
}

__global__ void k_fill(const int* dst, int* cnt, int* slots) {
    int e = blockIdx.x * blockDim.x + threadIdx.x;
    if (e < EN) {
        int d = dst[e];
        int p = atomicAdd(&cnt[d], 1);
        if (p < SLOTS_STRIDE) slots[d * SLOTS_STRIDE + p] = e;
    }
}

// FUSED: blocks 0..3 = per-node CSR sort + dinv; blocks 4..259 = mm1 (xw = mu @ W1)
struct FinMmSm {
    union {
        int buf[256][65];
        struct { float Wl[DIN * HD]; float xr[MMR4][DIN]; } m;
    } u;
};
__global__ __launch_bounds__(256) void k_finmm1(int* slots, const int* cnt, float* dinv,
                                                const float* mu, const float* W1, float* xw) {
    __shared__ FinMmSm sm;
    int tid = threadIdx.x;
    if (blockIdx.x < 4) {
        int t = blockIdx.x * 256 + tid;
        int n = cnt[t];
        if (n > SLOTS_STRIDE) n = SLOTS_STRIDE;
        for (int k = 0; k < n; k++) sm.u.buf[tid][k] = slots[t * SLOTS_STRIDE + k];
        for (int k = 1; k < n; k++) {
            int v = sm.u.buf[tid][k];
            int q = k - 1;
            while (q >= 0 && sm.u.buf[tid][q] > v) { sm.u.buf[tid][q + 1] = sm.u.buf[tid][q]; q--; }
            sm.u.buf[tid][q + 1] = v;
        }
        for (int k = 0; k < n; k++) slots[t * SLOTS_STRIDE + k] = sm.u.buf[tid][k];
        dinv[t] = 1.0f / sqrtf(fmaxf((float)(n + 1), 1e-12f));
    } else {
        int r0 = (blockIdx.x - 4) * MMR4;
        for (int idx = tid; idx < DIN * HD / 4; idx += 256)
            ((float4*)sm.u.m.Wl)[idx] = ((const float4*)W1)[idx];
        for (int idx = tid; idx < MMR4 * DIN / 4; idx += 256) {
            float4 v = ((const float4*)(mu + r0 * DIN))[idx];
            int row = (idx * 4) / DIN, col = (idx * 4) % DIN;
            sm.u.m.xr[row][col] = v.x; sm.u.m.xr[row][col + 1] = v.y;
            sm.u.m.xr[row][col + 2] = v.z; sm.u.m.xr[row][col + 3] = v.w;
        }
        __syncthreads();
        int col = tid & 127, half = tid >> 7;
        float a0 = 0.0f, a1 = 0.0f;
#pragma unroll 4
        for (int k = 0; k < DIN; k++) {
            float w = sm.u.m.Wl[k * HD + col];
            a0 = fmaf(sm.u.m.xr[half * 2 + 0][k], w, a0);
            a1 = fmaf(sm.u.m.xr[half * 2 + 1][k], w, a1);
        }
        xw[(r0 + half * 2 + 0) * HD + col] = a0;
        xw[(r0 + half * 2 + 1) * HD + col] = a1;
    }
}

// mm with LDS-staged W (K=128): 4 rows/block, 256 threads
__global__ __launch_bounds__(256) void k_mm128(const float* x, const float* W, float* out) {
    __shared__ float Wl[HD * HD];
    __shared__ float xr[MMR4][HD];
    int tid = threadIdx.x;
    int r0 = blockIdx.x * MMR4;
    for (int idx = tid; idx < HD * HD / 4; idx += 256)
        ((float4*)Wl)[idx] = ((const float4*)W)[idx];
    for (int idx = tid; idx < MMR4 * HD / 4; idx += 256) {
        float4 v = ((const float4*)(x + r0 * HD))[idx];
        int row = idx >> 5, col = (idx & 31) * 4;
        xr[row][col] = v.x; xr[row][col + 1] = v.y; xr[row][col + 2] = v.z; xr[row][col + 3] = v.w;
    }
    __syncthreads();
    int col = tid & 127, half = tid >> 7;
    float a0 = 0.0f, a1 = 0.0f;
#pragma unroll 4
    for (int k = 0; k < HD; k++) {
        float w = Wl[k * HD + col];
        a0 = fmaf(xr[half * 2 + 0][k], w, a0);
        a1 = fmaf(xr[half * 2 + 1][k], w, a1);
    }
    out[(r0 + half * 2 + 0) * HD + col] = a0;
    out[(r0 + half * 2 + 1) * HD + col] = a1;
}

// fused Aa/Cc with full Ws1 (128 KB) staged in LDS
__global__ __launch_bounds__(256) void k_mmAC(const float* h, const float* Ws1, const float* bs1,
                                              float* Aa, float* Cc) {
    __shared__ float Wl[2 * HD * HD];
    __shared__ float xr[MMR4][HD];
    int tid = threadIdx.x;
    int r0 = blockIdx.x * MMR4;
    for (int idx = tid; idx < 2 * HD * HD / 4; idx += 256)
        ((float4*)Wl)[idx] = ((const float4*)Ws1)[idx];
    for (int idx = tid; idx < MMR4 * HD / 4; idx += 256) {
        float4 v = ((const float4*)(h + r0 * HD))[idx];
        int row = idx >> 5, col = (idx & 31) * 4;
        xr[row][col] = v.x; xr[row][col + 1] = v.y; xr[row][col + 2] = v.z; xr[row][col + 3] = v.w;
    }
    __syncthreads();
    int col = tid & 127, half = tid >> 7;
    float bc = bs1[col];
    float A0 = 0.0f, A1 = 0.0f, C0 = bc, C1 = bc;
#pragma unroll 2
    for (int k = 0; k < HD; k++) {
        float wa = Wl[k * HD + col];
        float wc = Wl[(HD + k) * HD + col];
        A0 = fmaf(xr[half * 2 + 0][k], wa, A0);
        A1 = fmaf(xr[half * 2 + 1][k], wa, A1);
        C0 = fmaf(xr[half * 2 + 0][k], wc, C0);
        C1 = fmaf(xr[half * 2 + 1][k], wc, C1);
    }
    Aa[(r0 + half * 2 + 0) * HD + col] = A0;
    Aa[(r0 + half * 2 + 1) * HD + col] = A1;
    Cc[(r0 + half * 2 + 0) * HD + col] = C0;
    Cc[(r0 + half * 2 + 1) * HD + col] = C1;
}

// GCN gather: parallel edge-list prefetch + unrolled accumulate
__global__ __launch_bounds__(128) void k_gather(const float* xw, const float* bvec, const int* src,
                                                const int* slots, const int* cnt,
                                                const float* dinv, float* hout) {
    __shared__ int sn_s[SLOTS_STRIDE];
    __shared__ float w_s[SLOTS_STRIDE];
    int d = blockIdx.x, t = threadIdx.x;
    float dd = dinv[d];
    int n = cnt[d];
    if (n > SLOTS_STRIDE) n = SLOTS_STRIDE;
    if (t < n) {
        int e = slots[d * SLOTS_STRIDE + t];
        int sn = src[e];
        sn_s[t] = sn;
        w_s[t] = dinv[sn] * dd;
    }
    __syncthreads();
    float acc = 0.0f;
#pragma unroll 4
    for (int s = 0; s < n; s++)
        acc = fmaf(xw[sn_s[s] * HD + t], w_s[s], acc);
    acc = fmaf(xw[d * HD + t], dd * dd, acc);
    acc += bvec[t];
    hout[d * HD + t] = fmaxf(acc, 0.0f);
}

__device__ __forceinline__ u64 edge_key(float w, int i, int j) {
    unsigned u = __float_as_uint(w);
    u = (u & 0x80000000u) ? ~u : (u | 0x80000000u);
    int a = i < j ? i : j, b = i < j ? j : i;
    unsigned packed = (unsigned)(a * BN + b);
    return ((u64)u << 20) | (u64)(0xFFFFFu - packed);
}

// scores + FUSED Boruvka round-1 best.
// Off-diagonal tiles: upper store coalesced; mirror store via LDS transpose
// (reuses the As buffer) -> coalesced row writes instead of 4KB-stride scatter.
__global__ __launch_bounds__(256) void k_scores(const float* Aa, const float* Cc,
                                                const float* Ws2, const float* bs2v,
                                                float* S, u64* best) {
    int bid = blockIdx.x;
    int bi = 0, rem = bid;
    while (rem >= 16 - bi) { rem -= 16 - bi; bi++; }
    int bj = bi + rem;
    __shared__ float As[64][68];
    __shared__ float Cs[64][68];
    __shared__ float w2[HD];
    __shared__ u64 rmax[64], cmax[64];
    int tid = threadIdx.x;
    int R = bi * 64, Cb = bj * 64;
    if (tid < HD) w2[tid] = Ws2[tid];
    if (tid < 64) { rmax[tid] = 0ull; cmax[tid] = 0ull; }
    int tx = tid & 15, ty = tid >> 4;
    float acc[4][4] = {};
    for (int half = 0; half < 2; half++) {
        int k0 = half * 64;
        __syncthreads();
        for (int f = tid; f < 1024; f += 256) {
            int row = f >> 4, kk4 = (f & 15) * 4;
            float4 a = *(const float4*)&Aa[(R + row) * HD + k0 + kk4];
            float4 c = *(const float4*)&Cc[(Cb + row) * HD + k0 + kk4];
            As[kk4 + 0][row] = a.x; As[kk4 + 1][row] = a.y;
            As[kk4 + 2][row] = a.z; As[kk4 + 3][row] = a.w;
            Cs[kk4 + 0][row] = c.x; Cs[kk4 + 1][row] = c.y;
            Cs[kk4 + 2][row] = c.z; Cs[kk4 + 3][row] = c.w;
        }
        __syncthreads();
        for (int kk = 0; kk < 64; kk++) {
            float4 av = *(const float4*)&As[kk][ty * 4];
            float4 cv = *(const float4*)&Cs[kk][tx * 4];
            float wk = w2[k0 + kk];
            float ar[4] = {av.x, av.y, av.z, av.w};
            float cr[4] = {cv.x, cv.y, cv.z, cv.w};
#pragma unroll
            for (int r = 0; r < 4; r++)
#pragma unroll
                for (int q = 0; q < 4; q++) {
                    float tv = fmaxf(ar[r] + cr[q], 0.0f);
                    acc[r][q] = fmaf(tv, wk, acc[r][q]);
                }
        }
    }
    float b2 = bs2v[0];
    u64 rloc[4] = {0ull, 0ull, 0ull, 0ull};
    u64 cloc[4] = {0ull, 0ull, 0ull, 0ull};
    if (bi != bj) {
        __syncthreads();  // As dead after k-loop; reuse as transpose tile
#pragma unroll
        for (int r = 0; r < 4; r++)
#pragma unroll
            for (int q = 0; q < 4; q++) {
                int gr = R + ty * 4 + r, gc = Cb + tx * 4 + q;
                float v = acc[r][q] + b2;       // gr < gc always (off-diag)
                S[gr * BN + gc] = v;            // coalesced upper store
                As[tx * 4 + q][ty * 4 + r] = v; // LDS transpose deposit
                u64 key = edge_key(v, gr, gc);
                if (key > rloc[r]) rloc[r] = key;
                if (key > cloc[q]) cloc[q] = key;
            }
#pragma unroll
        for (int r = 0; r < 4; r++) {
            if (rloc[r]) atomicMax(&rmax[ty * 4 + r], rloc[r]);
            if (cloc[r]) atomicMax(&cmax[tx * 4 + r], cloc[r]);
        }
        __syncthreads();
        // coalesced transposed store: thread -> row2 = tid/4, cols (tid%4)*16..+15
        {
            int row2 = tid >> 2;
            int c0 = (tid & 3) * 16;
            float* dst = &S[(size_t)(Cb + row2) * BN + R + c0];
#pragma unroll
            for (int kk = 0; kk < 16; kk++) dst[kk] = As[row2][c0 + kk];
        }
    } else {
        // diagonal tile: original guarded path (within-tile mirror is small)
#pragma unroll
        for (int r = 0; r < 4; r++)
#pragma unroll
            for (int q = 0; q < 4; q++) {
                int gr = R + ty * 4 + r, gc = Cb + tx * 4 + q;
                float v = acc[r][q] + b2;
                if (gr < gc) {
                    S[gr * BN + gc] = v;
                    S[gc * BN + gr] = v;
                    u64 key = edge_key(v, gr, gc);
                    if (key > rloc[r]) rloc[r] = key;
                    if (key > cloc[q]) cloc[q] = key;
                } else if (gr == gc) S[gr * BN + gc] = 0.0f;
            }
#pragma unroll
        for (int r = 0; r < 4; r++) {
            if (rloc[r]) atomicMax(&rmax[ty * 4 + r], rloc[r]);
            if (cloc[r]) atomicMax(&cmax[tx * 4 + r], cloc[r]);
        }
        __syncthreads();
    }
    if (tid < 64) {
        if (rmax[tid]) atomicMax(&best[R + tid], rmax[tid]);
    } else if (tid < 128) {
        if (cmax[tid - 64]) atomicMax(&best[Cb + tid - 64], cmax[tid - 64]);
    }
}

// wave-per-row best-outgoing-edge scan (exact); optional ncomp guard
__global__ __launch_bounds__(256) void k_best(const float* S, const int* comp,
                                              u64* best, const int* mstcnt,
                                              const int* ncompG, int ncGuard) {
    if (*mstcnt >= BN - 1) return;
    if (ncGuard && *ncompG <= NC) return;
    int lane = threadIdx.x & 63;
    int i = blockIdx.x * 4 + (threadIdx.x >> 6);
    int ci = comp[i];
    const float* Srow = S + (size_t)i * BN;
    u64 loc = 0ull;
#pragma unroll 4
    for (int j = lane; j < BN; j += 64)
        if (comp[j] != ci) {
            u64 key = edge_key(Srow[j], i, j);
            if (key > loc) loc = key;
        }
#pragma unroll
    for (int off = 32; off > 0; off >>= 1) {
        u64 o = __shfl_xor(loc, off);
        if (o > loc) loc = o;
    }
    if (lane == 0 && loc) atomicMax(&best[ci], loc);
}

// round-1 merge: comp=identity; alternating-buffer doubling (1 barrier/iter)
__global__ __launch_bounds__(1024) void k_merge1(u64* best, int* comp, u64* mst, int* mstcnt) {
    __shared__ int pa[BN], pb[BN];
    int c = threadIdx.x;
    u64 e = best[c];
    unsigned packed = 0xFFFFFu - (unsigned)(e & 0xFFFFFu);
    int a = packed >> 10, b = packed & 1023;
    int t = (a == c) ? b : a;
    pa[c] = t;
    __syncthreads();
    bool mutual = (pa[t] == c);
    int p0 = pa[c];
    if (mutual && c < t) p0 = c;
    __syncthreads();
    pa[c] = p0;
    __syncthreads();
    if (!(mutual && c > t)) {
        int idx = atomicAdd(mstcnt, 1);
        mst[idx] = e;
    }
    int* A = pa;
    int* B = pb;
    for (int it = 0; it < 10; it++) {       // even count -> final state in pa
        B[c] = A[A[c]];
        __syncthreads();
        int* tm = A; A = B; B = tm;
    }
    comp[c] = A[c];
    best[c] = 0ull;
}

// generic merge: alternating doubling + ballot dense renumber (emitDense)
__global__ __launch_bounds__(1024) void k_merge(int* comp, u64* best, u64* mst, int* mstcnt,
                                                int* compD, int* ncompG, int emitDense,
                                                int ncGuard) {
    __shared__ int pa[BN], pb[BN];
    __shared__ u64 masksS[16];
    int c = threadIdx.x;
    if (*mstcnt >= BN - 1) return;
    if (ncGuard && *ncompG <= NC) return;
    int myComp = comp[c];
    bool root = (myComp == c);
    u64 e = best[c];
    int t = c;
    if (root && e) {
        unsigned packed = 0xFFFFFu - (unsigned)(e & 0xFFFFFu);
        int a = packed >> 10, b = packed & 1023;
        int ca = comp[a], cb = comp[b];
        t = (ca == c) ? cb : ca;
    }
    pa[c] = (root && e) ? t : c;
    __syncthreads();
    bool mutual = root && e && (pa[t] == c);
    int p0 = pa[c];
    if (mutual && c < t) p0 = c;
    __syncthreads();
    pa[c] = p0;
    __syncthreads();
    if (root && e && !(mutual && c > t)) {
        int idx = atomicAdd(mstcnt, 1);
        mst[idx] = e;
    }
    int* A = pa;
    int* B = pb;
    for (int it = 0; it < 10; it++) {
        B[c] = A[A[c]];
        __syncthreads();
        int* tm = A; A = B; B = tm;
    }
    comp[c] = A[myComp];
    best[c] = 0ull;
    if (!emitDense) return;
    // ballot-based dense renumber: 2 barriers total
    int lane = c & 63, wv = c >> 6;
    u64 m = __ballot(comp[c] == c);
    if (lane == 0) masksS[wv] = m;
    __syncthreads();
    int r = comp[c];
    int chunk = r >> 6;
    int rk = 0;
    for (int k = 0; k < chunk; k++) rk += __popcll(masksS[k]);
    rk += __popcll(masksS[chunk] & ((1ull << (r & 63)) - 1ull));
    compD[c] = rk;
    if (c == 0) {
        int t2 = 0;
        for (int k = 0; k < 16; k++) t2 += __popcll(masksS[k]);
        *ncompG = t2;
    }
}

// fused G+Sp: per-row LDS table -> global atomicMax into sp[c1][c2] (pre-zeroed)
__global__ __launch_bounds__(256) void k_Gsp(const float* S, const int* compD,
                                             const int* mstcnt, u64* spG) {
    if (*mstcnt >= BN - 1) return;
    __shared__ u64 t[NC];
    int tid = threadIdx.x;
    int i = blockIdx.x;
    int ci = compD[i];
    if (tid < NC) t[tid] = 0ull;
    __syncthreads();
    const float* Srow = S + (size_t)i * BN;
#pragma unroll 2
    for (int j = tid; j < BN; j += 256) {
        int cj = compD[j];
        if (j != i && cj != ci) atomicMax(&t[cj], edge_key(Srow[j], i, j));
    }
    __syncthreads();
    if (tid < NC && t[tid]) atomicMax(&spG[(size_t)ci * NC + tid], t[tid]);
}

struct FinSm {
    union {
        u64 sp[NC][NC];
        u64 sk[BN];
    } u;
    int cnd[BN];
    int ccomp[NC], cpa[NC], cpb[NC];
    u64 cbest[NC];
    int lcnt;
};

// remaining Boruvka rounds on the contracted (<=128 node) graph + finale
__global__ __launch_bounds__(1024) void k_mstfin(const u64* spG, const int* compD,
                                                 const int* ncompG, const int* mstcntG,
                                                 u64* mstG, float* out, int* pairs) {
    __shared__ FinSm sm;
    int c = threadIdx.x;
    int total = *mstcntG;
    if (total < BN - 1) {
        int nc = *ncompG;
        for (int idx = c; idx < NC * NC; idx += 1024) ((u64*)sm.u.sp)[idx] = spG[idx];
        sm.cnd[c] = compD[c];
        if (c < NC) { sm.ccomp[c] = c; sm.cbest[c] = 0ull; }
        if (c == 0) sm.lcnt = 0;
        __syncthreads();
        for (int rr = 0; rr < 8 && total < BN - 1; rr++) {
            if (c < nc) {
                int g = sm.ccomp[c];
                u64 m = 0ull;
                for (int c2 = 0; c2 < nc; c2++)
                    if (sm.ccomp[c2] != g) {
                        u64 v = sm.u.sp[c][c2];
                        if (v > m) m = v;
                    }
                if (m) atomicMax(&sm.cbest[g], m);
            }
            __syncthreads();
            if (c < nc) {
                bool root = (sm.ccomp[c] == c);
                u64 e = sm.cbest[c];
                int t2 = c;
                if (root && e) {
                    unsigned packed = 0xFFFFFu - (unsigned)(e & 0xFFFFFu);
                    int a = packed >> 10, b = packed & 1023;
                    int ga = sm.ccomp[sm.cnd[a]], gb = sm.ccomp[sm.cnd[b]];
                    t2 = (ga == c) ? gb : ga;
                }
                sm.cpa[c] = (root && e) ? t2 : c;
            }
            __syncthreads();
            if (c < nc) {
                bool root = (sm.ccomp[c] == c);
                u64 e = sm.cbest[c];
                int t2 = sm.cpa[c];
                bool mutual = root && e && (sm.cpa[t2] == c);
                int p0 = sm.cpa[c];
                if (mutual && c < t2) p0 = c;
                sm.cpb[c] = p0;
                if (root && e && !(mutual && c > t2)) {
                    int idx = total + atomicAdd(&sm.lcnt, 1);
                    mstG[idx] = e;
                }
            }
            __syncthreads();
            if (c < nc) sm.cpa[c] = sm.cpb[c];
            __syncthreads();
            {
                int* X = sm.cpa;
                int* Y = sm.cpb;
                for (int it = 0; it < 8; it++) {   // even count -> final state in cpa
                    if (c < nc) Y[c] = X[X[c]];
                    __syncthreads();
                    int* tm = X; X = Y; Y = tm;
                }
            }
            if (c < nc) {
                sm.ccomp[c] = sm.cpa[sm.ccomp[c]];
                sm.cbest[c] = 0ull;
            }
            __syncthreads();
            int added = sm.lcnt;
            __syncthreads();
            total += added;
            if (c == 0) sm.lcnt = 0;
            __syncthreads();
        }
    }
    __syncthreads();
    sm.u.sk[c] = (c < BN - 1) ? mstG[c] : 0ull;
    __syncthreads();
    if (c < BN - 1) {
        u64 mykey = sm.u.sk[c];
        int rk = 0;
        for (int f = 0; f < BN - 1; f++) rk += (sm.u.sk[f] > mykey) ? 1 : 0;
        unsigned packed = 0xFFFFFu - (unsigned)(mykey & 0xFFFFFu);
        int i = packed >> 10, j2 = packed & 1023;
        out[2 * rk] = (float)i;
        out[2 * rk + 1] = (float)j2;
        out[2046 + 2 * rk] = (float)j2;
        out[2046 + 2 * rk + 1] = (float)i;
        pairs[2 * rk] = i;
        pairs[2 * rk + 1] = j2;
    }
}

// 8 edges/block: W loads amortized 8x, 4 independent fma chains/thread
__global__ __launch_bounds__(256) void k_gamma8(const float* h, const int* pairs,
                                                const float* Wg1, const float* bg1,
                                                const float* Wg2, const float* bg2, float* out) {
    __shared__ float hp[EGR][2 * HD];
    __shared__ float z1[EGR][HD];
    int tid = threadIdx.x;
    int e0 = blockIdx.x * EGR;
    for (int idx = tid; idx < EGR * 2 * HD; idx += 256) {
        int eo = idx >> 8;
        int k = idx & 255;
        int e = e0 + eo;
        if (e < BN - 1) {
            int node = (k < HD) ? pairs[2 * e] : pairs[2 * e + 1];
            hp[eo][k] = h[node * HD + (k & 127)];
        }
    }
    __syncthreads();
    {
        int c = tid & 127, eg = tid >> 7;
        float b = bg1[c];
        float a0 = b, a1 = b, a2 = b, a3 = b;
#pragma unroll 4
        for (int k = 0; k < 2 * HD; k++) {
            float w = Wg1[k * HD + c];
            a0 = fmaf(hp[eg * 4 + 0][k], w, a0);
            a1 = fmaf(hp[eg * 4 + 1][k], w, a1);
            a2 = fmaf(hp[eg * 4 + 2][k], w, a2);
            a3 = fmaf(hp[eg * 4 + 3][k], w, a3);
        }
        z1[eg * 4 + 0][c] = fmaxf(a0, 0.0f);
        z1[eg * 4 + 1][c] = fmaxf(a1, 0.0f);
        z1[eg * 4 + 2][c] = fmaxf(a2, 0.0f);
        z1[eg * 4 + 3][c] = fmaxf(a3, 0.0f);
    }
    __syncthreads();
    {
        int co = tid & 63, eh = tid >> 6;
        float b = bg2[co];
        float g0 = b, g1 = b;
#pragma unroll 4
        for (int k = 0; k < HD; k++) {
            float w = Wg2[k * DIN + co];
            g0 = fmaf(z1[eh * 2 + 0][k], w, g0);
            g1 = fmaf(z1[eh * 2 + 1][k], w, g1);
        }
        int ea = e0 + eh * 2, eb = ea + 1;
        if (ea < BN - 1) out[4092 + ea * DIN + co] = tanhf(g0);
        if (eb < BN - 1) out[4092 + eb * DIN + co] = tanhf(g1);
    }
}

extern "C" void kernel_launch(void* const* d_in, const int* in_sizes, int n_in,
                              void* d_out, int out_size, void* d_ws, size_t ws_size,
                              hipStream_t stream) {
    const float* mu  = (const float*)d_in[0];
    const int*   ei  = (const int*)d_in[1];
    const float* W1  = (const float*)d_in[2];
    const float* b1  = (const float*)d_in[3];
    const float* W2  = (const float*)d_in[4];
    const float* b2  = (const float*)d_in[5];
    const float* Ws1 = (const float*)d_in[6];
    const float* bs1 = (const float*)d_in[7];
    const float* Ws2 = (const float*)d_in[8];
    const float* bs2 = (const float*)d_in[9];
    const float* Wg1 = (const float*)d_in[10];
    const float* bg1 = (const float*)d_in[11];
    const float* Wg2 = (const float*)d_in[12];
    const float* bg2 = (const float*)d_in[13];
    float* out = (float*)d_out;

    const int* src = ei;
    const int* dst = ei + EN;

    char* ws = (char*)d_ws;
    int*   slots = (int*)(ws);                      // 256 KiB (aliases S, dead pre-scores)
    float* S     = (float*)(ws);                    // 4 MiB, born at k_scores
    float* xw    = (float*)(ws + 4194304);
    float* h1    = (float*)(ws + 4718592);
    float* h2    = (float*)(ws + 5242880);
    float* Aa    = (float*)(ws + 5767168);
    float* Cc    = (float*)(ws + 6291456);
    // contiguous zero region: [cnt | best | mstcnt | spG] = 147456 B
    int*   cnt   = (int*)(ws + 6815744);
    u64*   best  = (u64*)(ws + 6819840);
    int*   mstcnt = (int*)(ws + 6828032);
    u64*   spG   = (u64*)(ws + 6832128);
    // end zero region
    int*   comp  = (int*)(ws + 6963200);
    u64*   mstG  = (u64*)(ws + 6967296);
    int*   pairs = (int*)(ws + 6975488);
    int*   compD = (int*)(ws + 6983680);
    int*   ncomp = (int*)(ws + 6987776);
    float* dinv  = (float*)(ws + 6991872);

    k_zero<<<36, 256, 0, stream>>>((float4*)(ws + 6815744));

    k_fill<<<EN / 256, 256, 0, stream>>>(dst, cnt, slots);
    k_finmm1<<<260, 256, 0, stream>>>(slots, cnt, dinv, mu, W1, xw);
    k_gather<<<BN, HD, 0, stream>>>(xw, b1, src, slots, cnt, dinv, h1);
    k_mm128<<<BN / MMR4, 256, 0, stream>>>(h1, W2, xw);
    k_gather<<<BN, HD, 0, stream>>>(xw, b2, src, slots, cnt, dinv, h2);

    k_mmAC<<<BN / MMR4, 256, 0, stream>>>(h2, Ws1, bs1, Aa, Cc);

    k_scores<<<136, 256, 0, stream>>>(Aa, Cc, Ws2, bs2, S, best);

    k_merge1<<<1, 1024, 0, stream>>>(best, comp, mstG, mstcnt);
    k_best<<<BN / 4, 256, 0, stream>>>(S, comp, best, mstcnt, ncomp, 0);
    k_merge<<<1, 1024, 0, stream>>>(comp, best, mstG, mstcnt, compD, ncomp, 1, 0);
    k_best<<<BN / 4, 256, 0, stream>>>(S, comp, best, mstcnt, ncomp, 1);
    k_merge<<<1, 1024, 0, stream>>>(comp, best, mstG, mstcnt, compD, ncomp, 1, 1);

    k_Gsp<<<BN, 256, 0, stream>>>(S, compD, mstcnt, spG);
    k_mstfin<<<1, 1024, 0, stream>>>(spG, compD, ncomp, mstcnt, mstG, out, pairs);

    k_gamma8<<<(BN - 1 + EGR - 1) / EGR, 256, 0, stream>>>(h2, pairs, Wg1, bg1, Wg2, bg2, out);
}

// Round 20
// 150.702 us; speedup vs baseline: 1.2491x; 1.0106x over previous
//
#include <hip/hip_runtime.h>
#include <hip/hip_bf16.h>
#include <math.h>

#define BN 1024
#define DIN 64
#define HD 128
#define EN 8192
#define SLOTS_STRIDE 64
#define MMR4 4
#define EGR 8
#define NC 128

typedef unsigned long long u64;

// zero the [cnt | best | mstcnt | spG] region: 147456 B = 9216 float4 (36 blocks x 256)
__global__ __launch_bounds__(256) void k_zero(float4* p) {
    int i = blockIdx.x * 256 + threadIdx.x;
    p[i] = make_float4(0.0f, 0.0f, 0.0f, 0.0f);
}

__global__ void k_fill(const int* dst, int* cnt, int* slots) {
    int e = blockIdx.x * blockDim.x + threadIdx.x;
    if (e < EN) {
        int d = dst[e];
        int p = atomicAdd(&cnt[d], 1);
        if (p < SLOTS_STRIDE) slots[d * SLOTS_STRIDE + p] = e;
    }
}

// FUSED: blocks 0..3 = per-node CSR sort + dinv; blocks 4..259 = mm1 (xw = mu @ W1)
struct FinMmSm {
    union {
        int buf[256][65];
        struct { float Wl[DIN * HD]; float xr[MMR4][DIN]; } m;
    } u;
};
__global__ __launch_bounds__(256) void k_finmm1(int* slots, const int* cnt, float* dinv,
                                                const float* mu, const float* W1, float* xw) {
    __shared__ FinMmSm sm;
    int tid = threadIdx.x;
    if (blockIdx.x < 4) {
        int t = blockIdx.x * 256 + tid;
        int n = cnt[t];
        if (n > SLOTS_STRIDE) n = SLOTS_STRIDE;
        for (int k = 0; k < n; k++) sm.u.buf[tid][k] = slots[t * SLOTS_STRIDE + k];
        for (int k = 1; k < n; k++) {
            int v = sm.u.buf[tid][k];
            int q = k - 1;
            while (q >= 0 && sm.u.buf[tid][q] > v) { sm.u.buf[tid][q + 1] = sm.u.buf[tid][q]; q--; }
            sm.u.buf[tid][q + 1] = v;
        }
        for (int k = 0; k < n; k++) slots[t * SLOTS_STRIDE + k] = sm.u.buf[tid][k];
        dinv[t] = 1.0f / sqrtf(fmaxf((float)(n + 1), 1e-12f));
    } else {
        int r0 = (blockIdx.x - 4) * MMR4;
        for (int idx = tid; idx < DIN * HD / 4; idx += 256)
            ((float4*)sm.u.m.Wl)[idx] = ((const float4*)W1)[idx];
        for (int idx = tid; idx < MMR4 * DIN / 4; idx += 256) {
            float4 v = ((const float4*)(mu + r0 * DIN))[idx];
            int row = (idx * 4) / DIN, col = (idx * 4) % DIN;
            sm.u.m.xr[row][col] = v.x; sm.u.m.xr[row][col + 1] = v.y;
            sm.u.m.xr[row][col + 2] = v.z; sm.u.m.xr[row][col + 3] = v.w;
        }
        __syncthreads();
        int col = tid & 127, half = tid >> 7;
        float a0 = 0.0f, a1 = 0.0f;
#pragma unroll 4
        for (int k = 0; k < DIN; k++) {
            float w = sm.u.m.Wl[k * HD + col];
            a0 = fmaf(sm.u.m.xr[half * 2 + 0][k], w, a0);
            a1 = fmaf(sm.u.m.xr[half * 2 + 1][k], w, a1);
        }
        xw[(r0 + half * 2 + 0) * HD + col] = a0;
        xw[(r0 + half * 2 + 1) * HD + col] = a1;
    }
}

// mm with LDS-staged W (K=128): 4 rows/block, 256 threads
__global__ __launch_bounds__(256) void k_mm128(const float* x, const float* W, float* out) {
    __shared__ float Wl[HD * HD];
    __shared__ float xr[MMR4][HD];
    int tid = threadIdx.x;
    int r0 = blockIdx.x * MMR4;
    for (int idx = tid; idx < HD * HD / 4; idx += 256)
        ((float4*)Wl)[idx] = ((const float4*)W)[idx];
    for (int idx = tid; idx < MMR4 * HD / 4; idx += 256) {
        float4 v = ((const float4*)(x + r0 * HD))[idx];
        int row = idx >> 5, col = (idx & 31) * 4;
        xr[row][col] = v.x; xr[row][col + 1] = v.y; xr[row][col + 2] = v.z; xr[row][col + 3] = v.w;
    }
    __syncthreads();
    int col = tid & 127, half = tid >> 7;
    float a0 = 0.0f, a1 = 0.0f;
#pragma unroll 4
    for (int k = 0; k < HD; k++) {
        float w = Wl[k * HD + col];
        a0 = fmaf(xr[half * 2 + 0][k], w, a0);
        a1 = fmaf(xr[half * 2 + 1][k], w, a1);
    }
    out[(r0 + half * 2 + 0) * HD + col] = a0;
    out[(r0 + half * 2 + 1) * HD + col] = a1;
}

// fused Aa/Cc with full Ws1 (128 KB) staged in LDS
__global__ __launch_bounds__(256) void k_mmAC(const float* h, const float* Ws1, const float* bs1,
                                              float* Aa, float* Cc) {
    __shared__ float Wl[2 * HD * HD];
    __shared__ float xr[MMR4][HD];
    int tid = threadIdx.x;
    int r0 = blockIdx.x * MMR4;
    for (int idx = tid; idx < 2 * HD * HD / 4; idx += 256)
        ((float4*)Wl)[idx] = ((const float4*)Ws1)[idx];
    for (int idx = tid; idx < MMR4 * HD / 4; idx += 256) {
        float4 v = ((const float4*)(h + r0 * HD))[idx];
        int row = idx >> 5, col = (idx & 31) * 4;
        xr[row][col] = v.x; xr[row][col + 1] = v.y; xr[row][col + 2] = v.z; xr[row][col + 3] = v.w;
    }
    __syncthreads();
    int col = tid & 127, half = tid >> 7;
    float bc = bs1[col];
    float A0 = 0.0f, A1 = 0.0f, C0 = bc, C1 = bc;
#pragma unroll 2
    for (int k = 0; k < HD; k++) {
        float wa = Wl[k * HD + col];
        float wc = Wl[(HD + k) * HD + col];
        A0 = fmaf(xr[half * 2 + 0][k], wa, A0);
        A1 = fmaf(xr[half * 2 + 1][k], wa, A1);
        C0 = fmaf(xr[half * 2 + 0][k], wc, C0);
        C1 = fmaf(xr[half * 2 + 1][k], wc, C1);
    }
    Aa[(r0 + half * 2 + 0) * HD + col] = A0;
    Aa[(r0 + half * 2 + 1) * HD + col] = A1;
    Cc[(r0 + half * 2 + 0) * HD + col] = C0;
    Cc[(r0 + half * 2 + 1) * HD + col] = C1;
}

// GCN gather: parallel edge-list prefetch + unrolled accumulate
__global__ __launch_bounds__(128) void k_gather(const float* xw, const float* bvec, const int* src,
                                                const int* slots, const int* cnt,
                                                const float* dinv, float* hout) {
    __shared__ int sn_s[SLOTS_STRIDE];
    __shared__ float w_s[SLOTS_STRIDE];
    int d = blockIdx.x, t = threadIdx.x;
    float dd = dinv[d];
    int n = cnt[d];
    if (n > SLOTS_STRIDE) n = SLOTS_STRIDE;
    if (t < n) {
        int e = slots[d * SLOTS_STRIDE + t];
        int sn = src[e];
        sn_s[t] = sn;
        w_s[t] = dinv[sn] * dd;
    }
    __syncthreads();
    float acc = 0.0f;
#pragma unroll 4
    for (int s = 0; s < n; s++)
        acc = fmaf(xw[sn_s[s] * HD + t], w_s[s], acc);
    acc = fmaf(xw[d * HD + t], dd * dd, acc);
    acc += bvec[t];
    hout[d * HD + t] = fmaxf(acc, 0.0f);
}

__device__ __forceinline__ u64 edge_key(float w, int i, int j) {
    unsigned u = __float_as_uint(w);
    u = (u & 0x80000000u) ? ~u : (u | 0x80000000u);
    int a = i < j ? i : j, b = i < j ? j : i;
    unsigned packed = (unsigned)(a * BN + b);
    return ((u64)u << 20) | (u64)(0xFFFFFu - packed);
}

// scores + FUSED Boruvka round-1 best; LDS-transposed mirror store
__global__ __launch_bounds__(256) void k_scores(const float* Aa, const float* Cc,
                                                const float* Ws2, const float* bs2v,
                                                float* S, u64* best) {
    int bid = blockIdx.x;
    int bi = 0, rem = bid;
    while (rem >= 16 - bi) { rem -= 16 - bi; bi++; }
    int bj = bi + rem;
    __shared__ float As[64][68];
    __shared__ float Cs[64][68];
    __shared__ float w2[HD];
    __shared__ u64 rmax[64], cmax[64];
    int tid = threadIdx.x;
    int R = bi * 64, Cb = bj * 64;
    if (tid < HD) w2[tid] = Ws2[tid];
    if (tid < 64) { rmax[tid] = 0ull; cmax[tid] = 0ull; }
    int tx = tid & 15, ty = tid >> 4;
    float acc[4][4] = {};
    for (int half = 0; half < 2; half++) {
        int k0 = half * 64;
        __syncthreads();
        for (int f = tid; f < 1024; f += 256) {
            int row = f >> 4, kk4 = (f & 15) * 4;
            float4 a = *(const float4*)&Aa[(R + row) * HD + k0 + kk4];
            float4 c = *(const float4*)&Cc[(Cb + row) * HD + k0 + kk4];
            As[kk4 + 0][row] = a.x; As[kk4 + 1][row] = a.y;
            As[kk4 + 2][row] = a.z; As[kk4 + 3][row] = a.w;
            Cs[kk4 + 0][row] = c.x; Cs[kk4 + 1][row] = c.y;
            Cs[kk4 + 2][row] = c.z; Cs[kk4 + 3][row] = c.w;
        }
        __syncthreads();
        for (int kk = 0; kk < 64; kk++) {
            float4 av = *(const float4*)&As[kk][ty * 4];
            float4 cv = *(const float4*)&Cs[kk][tx * 4];
            float wk = w2[k0 + kk];
            float ar[4] = {av.x, av.y, av.z, av.w};
            float cr[4] = {cv.x, cv.y, cv.z, cv.w};
#pragma unroll
            for (int r = 0; r < 4; r++)
#pragma unroll
                for (int q = 0; q < 4; q++) {
                    float tv = fmaxf(ar[r] + cr[q], 0.0f);
                    acc[r][q] = fmaf(tv, wk, acc[r][q]);
                }
        }
    }
    float b2 = bs2v[0];
    u64 rloc[4] = {0ull, 0ull, 0ull, 0ull};
    u64 cloc[4] = {0ull, 0ull, 0ull, 0ull};
    if (bi != bj) {
        __syncthreads();  // As dead after k-loop; reuse as transpose tile
#pragma unroll
        for (int r = 0; r < 4; r++)
#pragma unroll
            for (int q = 0; q < 4; q++) {
                int gr = R + ty * 4 + r, gc = Cb + tx * 4 + q;
                float v = acc[r][q] + b2;
                S[gr * BN + gc] = v;
                As[tx * 4 + q][ty * 4 + r] = v;
                u64 key = edge_key(v, gr, gc);
                if (key > rloc[r]) rloc[r] = key;
                if (key > cloc[q]) cloc[q] = key;
            }
#pragma unroll
        for (int r = 0; r < 4; r++) {
            if (rloc[r]) atomicMax(&rmax[ty * 4 + r], rloc[r]);
            if (cloc[r]) atomicMax(&cmax[tx * 4 + r], cloc[r]);
        }
        __syncthreads();
        {
            int row2 = tid >> 2;
            int c0 = (tid & 3) * 16;
            float* dst = &S[(size_t)(Cb + row2) * BN + R + c0];
#pragma unroll
            for (int kk = 0; kk < 16; kk++) dst[kk] = As[row2][c0 + kk];
        }
    } else {
#pragma unroll
        for (int r = 0; r < 4; r++)
#pragma unroll
            for (int q = 0; q < 4; q++) {
                int gr = R + ty * 4 + r, gc = Cb + tx * 4 + q;
                float v = acc[r][q] + b2;
                if (gr < gc) {
                    S[gr * BN + gc] = v;
                    S[gc * BN + gr] = v;
                    u64 key = edge_key(v, gr, gc);
                    if (key > rloc[r]) rloc[r] = key;
                    if (key > cloc[q]) cloc[q] = key;
                } else if (gr == gc) S[gr * BN + gc] = 0.0f;
            }
#pragma unroll
        for (int r = 0; r < 4; r++) {
            if (rloc[r]) atomicMax(&rmax[ty * 4 + r], rloc[r]);
            if (cloc[r]) atomicMax(&cmax[tx * 4 + r], cloc[r]);
        }
        __syncthreads();
    }
    if (tid < 64) {
        if (rmax[tid]) atomicMax(&best[R + tid], rmax[tid]);
    } else if (tid < 128) {
        if (cmax[tid - 64]) atomicMax(&best[Cb + tid - 64], cmax[tid - 64]);
    }
}

// wave-per-row best scan; comp[] staged in LDS (kills scattered L2 int reads)
__global__ __launch_bounds__(256) void k_best(const float* S, const int* comp,
                                              u64* best, const int* mstcnt,
                                              const int* ncompG, int ncGuard) {
    if (*mstcnt >= BN - 1) return;
    if (ncGuard && *ncompG <= NC) return;
    __shared__ int comp_s[BN];
    int tid = threadIdx.x;
    ((int4*)comp_s)[tid] = ((const int4*)comp)[tid];   // 256 x int4 = 1024 ints
    __syncthreads();
    int lane = tid & 63;
    int i = blockIdx.x * 4 + (tid >> 6);
    int ci = comp_s[i];
    const float* Srow = S + (size_t)i * BN;
    u64 loc = 0ull;
#pragma unroll 4
    for (int j = lane; j < BN; j += 64)
        if (comp_s[j] != ci) {
            u64 key = edge_key(Srow[j], i, j);
            if (key > loc) loc = key;
        }
#pragma unroll
    for (int off = 32; off > 0; off >>= 1) {
        u64 o = __shfl_xor(loc, off);
        if (o > loc) loc = o;
    }
    if (lane == 0 && loc) atomicMax(&best[ci], loc);
}

// round-1 merge: comp=identity; alternating-buffer doubling (1 barrier/iter)
__global__ __launch_bounds__(1024) void k_merge1(u64* best, int* comp, u64* mst, int* mstcnt) {
    __shared__ int pa[BN], pb[BN];
    int c = threadIdx.x;
    u64 e = best[c];
    unsigned packed = 0xFFFFFu - (unsigned)(e & 0xFFFFFu);
    int a = packed >> 10, b = packed & 1023;
    int t = (a == c) ? b : a;
    pa[c] = t;
    __syncthreads();
    bool mutual = (pa[t] == c);
    int p0 = pa[c];
    if (mutual && c < t) p0 = c;
    __syncthreads();
    pa[c] = p0;
    __syncthreads();
    if (!(mutual && c > t)) {
        int idx = atomicAdd(mstcnt, 1);
        mst[idx] = e;
    }
    int* A = pa;
    int* B = pb;
    for (int it = 0; it < 10; it++) {       // even count -> final state in pa
        B[c] = A[A[c]];
        __syncthreads();
        int* tm = A; A = B; B = tm;
    }
    comp[c] = A[c];
    best[c] = 0ull;
}

// generic merge: alternating doubling + ballot dense renumber (emitDense)
__global__ __launch_bounds__(1024) void k_merge(int* comp, u64* best, u64* mst, int* mstcnt,
                                                int* compD, int* ncompG, int emitDense,
                                                int ncGuard) {
    __shared__ int pa[BN], pb[BN];
    __shared__ u64 masksS[16];
    int c = threadIdx.x;
    if (*mstcnt >= BN - 1) return;
    if (ncGuard && *ncompG <= NC) return;
    int myComp = comp[c];
    bool root = (myComp == c);
    u64 e = best[c];
    int t = c;
    if (root && e) {
        unsigned packed = 0xFFFFFu - (unsigned)(e & 0xFFFFFu);
        int a = packed >> 10, b = packed & 1023;
        int ca = comp[a], cb = comp[b];
        t = (ca == c) ? cb : ca;
    }
    pa[c] = (root && e) ? t : c;
    __syncthreads();
    bool mutual = root && e && (pa[t] == c);
    int p0 = pa[c];
    if (mutual && c < t) p0 = c;
    __syncthreads();
    pa[c] = p0;
    __syncthreads();
    if (root && e && !(mutual && c > t)) {
        int idx = atomicAdd(mstcnt, 1);
        mst[idx] = e;
    }
    int* A = pa;
    int* B = pb;
    for (int it = 0; it < 10; it++) {
        B[c] = A[A[c]];
        __syncthreads();
        int* tm = A; A = B; B = tm;
    }
    comp[c] = A[myComp];
    best[c] = 0ull;
    if (!emitDense) return;
    // ballot-based dense renumber: 2 barriers total
    int lane = c & 63, wv = c >> 6;
    u64 m = __ballot(comp[c] == c);
    if (lane == 0) masksS[wv] = m;
    __syncthreads();
    int r = comp[c];
    int chunk = r >> 6;
    int rk = 0;
    for (int k = 0; k < chunk; k++) rk += __popcll(masksS[k]);
    rk += __popcll(masksS[chunk] & ((1ull << (r & 63)) - 1ull));
    compD[c] = rk;
    if (c == 0) {
        int t2 = 0;
        for (int k = 0; k < 16; k++) t2 += __popcll(masksS[k]);
        *ncompG = t2;
    }
}

// fused G+Sp: compD staged in LDS; per-row LDS table -> global atomicMax
__global__ __launch_bounds__(256) void k_Gsp(const float* S, const int* compD,
                                             const int* mstcnt, u64* spG) {
    if (*mstcnt >= BN - 1) return;
    __shared__ u64 t[NC];
    __shared__ int cd_s[BN];
    int tid = threadIdx.x;
    ((int4*)cd_s)[tid] = ((const int4*)compD)[tid];
    if (tid < NC) t[tid] = 0ull;
    __syncthreads();
    int i = blockIdx.x;
    int ci = cd_s[i];
    const float* Srow = S + (size_t)i * BN;
#pragma unroll 2
    for (int j = tid; j < BN; j += 256) {
        int cj = cd_s[j];
        if (j != i && cj != ci) atomicMax(&t[cj], edge_key(Srow[j], i, j));
    }
    __syncthreads();
    if (tid < NC && t[tid]) atomicMax(&spG[(size_t)ci * NC + tid], t[tid]);
}

struct FinSm {
    union {
        u64 sp[NC][NC];
        u64 sk[BN];
    } u;
    int cnd[BN];
    int ccomp[NC], cpa[NC], cpb[NC];
    u64 cbest[NC];
    int lcnt;
};

// remaining Boruvka rounds on the contracted (<=128 node) graph + finale
__global__ __launch_bounds__(1024) void k_mstfin(const u64* spG, const int* compD,
                                                 const int* ncompG, const int* mstcntG,
                                                 u64* mstG, float* out, int* pairs) {
    __shared__ FinSm sm;
    int c = threadIdx.x;
    int total = *mstcntG;
    if (total < BN - 1) {
        int nc = *ncompG;
        for (int idx = c; idx < NC * NC; idx += 1024) ((u64*)sm.u.sp)[idx] = spG[idx];
        sm.cnd[c] = compD[c];
        if (c < NC) { sm.ccomp[c] = c; sm.cbest[c] = 0ull; }
        if (c == 0) sm.lcnt = 0;
        __syncthreads();
        for (int rr = 0; rr < 8 && total < BN - 1; rr++) {
            if (c < nc) {
                int g = sm.ccomp[c];
                u64 m = 0ull;
                for (int c2 = 0; c2 < nc; c2++)
                    if (sm.ccomp[c2] != g) {
                        u64 v = sm.u.sp[c][c2];
                        if (v > m) m = v;
                    }
                if (m) atomicMax(&sm.cbest[g], m);
            }
            __syncthreads();
            if (c < nc) {
                bool root = (sm.ccomp[c] == c);
                u64 e = sm.cbest[c];
                int t2 = c;
                if (root && e) {
                    unsigned packed = 0xFFFFFu - (unsigned)(e & 0xFFFFFu);
                    int a = packed >> 10, b = packed & 1023;
                    int ga = sm.ccomp[sm.cnd[a]], gb = sm.ccomp[sm.cnd[b]];
                    t2 = (ga == c) ? gb : ga;
                }
                sm.cpa[c] = (root && e) ? t2 : c;
            }
            __syncthreads();
            if (c < nc) {
                bool root = (sm.ccomp[c] == c);
                u64 e = sm.cbest[c];
                int t2 = sm.cpa[c];
                bool mutual = root && e && (sm.cpa[t2] == c);
                int p0 = sm.cpa[c];
                if (mutual && c < t2) p0 = c;
                sm.cpb[c] = p0;
                if (root && e && !(mutual && c > t2)) {
                    int idx = total + atomicAdd(&sm.lcnt, 1);
                    mstG[idx] = e;
                }
            }
            __syncthreads();
            if (c < nc) sm.cpa[c] = sm.cpb[c];
            __syncthreads();
            {
                int* X = sm.cpa;
                int* Y = sm.cpb;
                for (int it = 0; it < 8; it++) {   // even count -> final state in cpa
                    if (c < nc) Y[c] = X[X[c]];
                    __syncthreads();
                    int* tm = X; X = Y; Y = tm;
                }
            }
            if (c < nc) {
                sm.ccomp[c] = sm.cpa[sm.ccomp[c]];
                sm.cbest[c] = 0ull;
            }
            __syncthreads();
            int added = sm.lcnt;
            __syncthreads();
            total += added;
            if (c == 0) sm.lcnt = 0;
            __syncthreads();
        }
    }
    __syncthreads();
    sm.u.sk[c] = (c < BN - 1) ? mstG[c] : 0ull;
    __syncthreads();
    if (c < BN - 1) {
        u64 mykey = sm.u.sk[c];
        int rk = 0;
        for (int f = 0; f < BN - 1; f++) rk += (sm.u.sk[f] > mykey) ? 1 : 0;
        unsigned packed = 0xFFFFFu - (unsigned)(mykey & 0xFFFFFu);
        int i = packed >> 10, j2 = packed & 1023;
        out[2 * rk] = (float)i;
        out[2 * rk + 1] = (float)j2;
        out[2046 + 2 * rk] = (float)j2;
        out[2046 + 2 * rk + 1] = (float)i;
        pairs[2 * rk] = i;
        pairs[2 * rk + 1] = j2;
    }
}

// 8 edges/block: W loads amortized 8x, 4 independent fma chains/thread
__global__ __launch_bounds__(256) void k_gamma8(const float* h, const int* pairs,
                                                const float* Wg1, const float* bg1,
                                                const float* Wg2, const float* bg2, float* out) {
    __shared__ float hp[EGR][2 * HD];
    __shared__ float z1[EGR][HD];
    int tid = threadIdx.x;
    int e0 = blockIdx.x * EGR;
    for (int idx = tid; idx < EGR * 2 * HD; idx += 256) {
        int eo = idx >> 8;
        int k = idx & 255;
        int e = e0 + eo;
        if (e < BN - 1) {
            int node = (k < HD) ? pairs[2 * e] : pairs[2 * e + 1];
            hp[eo][k] = h[node * HD + (k & 127)];
        }
    }
    __syncthreads();
    {
        int c = tid & 127, eg = tid >> 7;
        float b = bg1[c];
        float a0 = b, a1 = b, a2 = b, a3 = b;
#pragma unroll 4
        for (int k = 0; k < 2 * HD; k++) {
            float w = Wg1[k * HD + c];
            a0 = fmaf(hp[eg * 4 + 0][k], w, a0);
            a1 = fmaf(hp[eg * 4 + 1][k], w, a1);
            a2 = fmaf(hp[eg * 4 + 2][k], w, a2);
            a3 = fmaf(hp[eg * 4 + 3][k], w, a3);
        }
        z1[eg * 4 + 0][c] = fmaxf(a0, 0.0f);
        z1[eg * 4 + 1][c] = fmaxf(a1, 0.0f);
        z1[eg * 4 + 2][c] = fmaxf(a2, 0.0f);
        z1[eg * 4 + 3][c] = fmaxf(a3, 0.0f);
    }
    __syncthreads();
    {
        int co = tid & 63, eh = tid >> 6;
        float b = bg2[co];
        float g0 = b, g1 = b;
#pragma unroll 4
        for (int k = 0; k < HD; k++) {
            float w = Wg2[k * DIN + co];
            g0 = fmaf(z1[eh * 2 + 0][k], w, g0);
            g1 = fmaf(z1[eh * 2 + 1][k], w, g1);
        }
        int ea = e0 + eh * 2, eb = ea + 1;
        if (ea < BN - 1) out[4092 + ea * DIN + co] = tanhf(g0);
        if (eb < BN - 1) out[4092 + eb * DIN + co] = tanhf(g1);
    }
}

extern "C" void kernel_launch(void* const* d_in, const int* in_sizes, int n_in,
                              void* d_out, int out_size, void* d_ws, size_t ws_size,
                              hipStream_t stream) {
    const float* mu  = (const float*)d_in[0];
    const int*   ei  = (const int*)d_in[1];
    const float* W1  = (const float*)d_in[2];
    const float* b1  = (const float*)d_in[3];
    const float* W2  = (const float*)d_in[4];
    const float* b2  = (const float*)d_in[5];
    const float* Ws1 = (const float*)d_in[6];
    const float* bs1 = (const float*)d_in[7];
    const float* Ws2 = (const float*)d_in[8];
    const float* bs2 = (const float*)d_in[9];
    const float* Wg1 = (const float*)d_in[10];
    const float* bg1 = (const float*)d_in[11];
    const float* Wg2 = (const float*)d_in[12];
    const float* bg2 = (const float*)d_in[13];
    float* out = (float*)d_out;

    const int* src = ei;
    const int* dst = ei + EN;

    char* ws = (char*)d_ws;
    int*   slots = (int*)(ws);                      // 256 KiB (aliases S, dead pre-scores)
    float* S     = (float*)(ws);                    // 4 MiB, born at k_scores
    float* xw    = (float*)(ws + 4194304);
    float* h1    = (float*)(ws + 4718592);
    float* h2    = (float*)(ws + 5242880);
    float* Aa    = (float*)(ws + 5767168);
    float* Cc    = (float*)(ws + 6291456);
    // contiguous zero region: [cnt | best | mstcnt | spG] = 147456 B
    int*   cnt   = (int*)(ws + 6815744);
    u64*   best  = (u64*)(ws + 6819840);
    int*   mstcnt = (int*)(ws + 6828032);
    u64*   spG   = (u64*)(ws + 6832128);
    // end zero region
    int*   comp  = (int*)(ws + 6963200);
    u64*   mstG  = (u64*)(ws + 6967296);
    int*   pairs = (int*)(ws + 6975488);
    int*   compD = (int*)(ws + 6983680);
    int*   ncomp = (int*)(ws + 6987776);
    float* dinv  = (float*)(ws + 6991872);

    k_zero<<<36, 256, 0, stream>>>((float4*)(ws + 6815744));

    k_fill<<<EN / 256, 256, 0, stream>>>(dst, cnt, slots);
    k_finmm1<<<260, 256, 0, stream>>>(slots, cnt, dinv, mu, W1, xw);
    k_gather<<<BN, HD, 0, stream>>>(xw, b1, src, slots, cnt, dinv, h1);
    k_mm128<<<BN / MMR4, 256, 0, stream>>>(h1, W2, xw);
    k_gather<<<BN, HD, 0, stream>>>(xw, b2, src, slots, cnt, dinv, h2);

    k_mmAC<<<BN / MMR4, 256, 0, stream>>>(h2, Ws1, bs1, Aa, Cc);

    k_scores<<<136, 256, 0, stream>>>(Aa, Cc, Ws2, bs2, S, best);

    k_merge1<<<1, 1024, 0, stream>>>(best, comp, mstG, mstcnt);
    k_best<<<BN / 4, 256, 0, stream>>>(S, comp, best, mstcnt, ncomp, 0);
    k_merge<<<1, 1024, 0, stream>>>(comp, best, mstG, mstcnt, compD, ncomp, 1, 0);
    k_best<<<BN / 4, 256, 0, stream>>>(S, comp, best, mstcnt, ncomp, 1);
    k_merge<<<1, 1024, 0, stream>>>(comp, best, mstG, mstcnt, compD, ncomp, 1, 1);

    k_Gsp<<<BN, 256, 0, stream>>>(S, compD, mstcnt, spG);
    k_mstfin<<<1, 1024, 0, stream>>>(spG, compD, ncomp, mstcnt, mstG, out, pairs);

    k_gamma8<<<(BN - 1 + EGR - 1) / EGR, 256, 0, stream>>>(h2, pairs, Wg1, bg1, Wg2, bg2, out);
}